// Round 12
// baseline (193.299 us; speedup 1.0000x reference)
//
#include <hip/hip_runtime.h>
#include <math.h>

typedef float f32x4 __attribute__((ext_vector_type(4)));
typedef short bf16x8 __attribute__((ext_vector_type(8)));
typedef unsigned short u16;

__device__ __forceinline__ u16 f2bf(float f) {
    unsigned u = __builtin_bit_cast(unsigned, f);
    u += 0x7fff + ((u >> 16) & 1);   // RNE
    return (u16)(u >> 16);
}
__device__ __forceinline__ float bf2f(u16 s) {
    unsigned v = ((unsigned)s) << 16;
    return __builtin_bit_cast(float, v);
}
__device__ __forceinline__ void gload16(const void* g, void* l) {
    __builtin_amdgcn_global_load_lds(
        (const __attribute__((address_space(1))) unsigned int*)g,
        (__attribute__((address_space(3))) unsigned int*)l, 16, 0, 0);
}

// ---------------- K_pre: transpose_norm (512) | f2bf Wgk (2048) | Winp^T (512)
//                  | wgp partials (16) | cg (1)  -- no atomics, no memset needed
__global__ __launch_bounds__(256) void k_pre(const float* __restrict__ x,
                                             const float* __restrict__ Wgk,
                                             const float* __restrict__ Winp,
                                             const float* __restrict__ Wg,
                                             const float* __restrict__ binp,
                                             const float* __restrict__ bg,
                                             u16* __restrict__ xtn,
                                             u16* __restrict__ wgkb,
                                             u16* __restrict__ winpT,
                                             float* __restrict__ wgp,
                                             float* __restrict__ cg) {
    int bid = blockIdx.x, tid = threadIdx.x;
    if (bid < 512) {
        // x [32,1024,16,8] -> xtn[b][m][c] bf16, L2-normalized over c
        int b8 = bid >> 4, hh = bid & 15;
        __shared__ float tile[8][1032];
        __shared__ float inv[8];
        const float* src = x + (size_t)b8 * 1024 * 128 + hh * 8;
        #pragma unroll
        for (int r = 0; r < 4; ++r) {
            int c = tid * 4 + r;
            const float* p = src + (size_t)c * 128;
            float4 v0 = *(const float4*)(p);
            float4 v1 = *(const float4*)(p + 4);
            tile[0][c] = v0.x; tile[1][c] = v0.y; tile[2][c] = v0.z; tile[3][c] = v0.w;
            tile[4][c] = v1.x; tile[5][c] = v1.y; tile[6][c] = v1.z; tile[7][c] = v1.w;
        }
        __syncthreads();
        int w = tid >> 5, j = tid & 31;
        float s = 0.f;
        #pragma unroll 8
        for (int i = 0; i < 32; ++i) { float v = tile[w][i * 32 + j]; s += v * v; }
        #pragma unroll
        for (int m = 16; m; m >>= 1) s += __shfl_xor(s, m);
        if (j == 0) inv[w] = 1.0f / fmaxf(sqrtf(s), 1e-12f);
        __syncthreads();
        int b = b8 >> 3, t = b8 & 7;
        int c0 = tid * 4;
        for (int w2 = 0; w2 < 8; ++w2) {
            int m = t * 128 + hh * 8 + w2;
            float sc = inv[w2];
            u16* dst = xtn + ((size_t)b * 1024 + m) * 1024;
            ushort4 o;
            o.x = f2bf(tile[w2][c0 + 0] * sc);
            o.y = f2bf(tile[w2][c0 + 1] * sc);
            o.z = f2bf(tile[w2][c0 + 2] * sc);
            o.w = f2bf(tile[w2][c0 + 3] * sc);
            *(ushort4*)(dst + c0) = o;
        }
    } else if (bid < 2560) {
        int i = ((bid - 512) * 256 + tid) * 4;
        float4 v = *(const float4*)(Wgk + i);
        ushort4 o;
        o.x = f2bf(v.x); o.y = f2bf(v.y); o.z = f2bf(v.z); o.w = f2bf(v.w);
        *(ushort4*)(wgkb + i) = o;
    } else if (bid < 3072) {
        int tb = bid - 2560;            // 0..511
        int er = tb & 31, cr = tb >> 5; // e-tile(64), c-tile(64)
        __shared__ float tile[64][65];
        #pragma unroll
        for (int i = 0; i < 16; ++i) {
            int idx = tid + i * 256;
            int r = idx >> 6, c = idx & 63;
            tile[r][c] = Winp[(size_t)(er * 64 + r) * 1024 + cr * 64 + c];
        }
        __syncthreads();
        #pragma unroll
        for (int i = 0; i < 16; ++i) {
            int idx = tid + i * 256;
            int cc = idx >> 6, rr = idx & 63;
            winpT[(size_t)(cr * 64 + cc) * 2048 + er * 64 + rr] = f2bf(tile[rr][cc]);
        }
    } else if (bid < 3088) {
        // wgp[eq][g][c] = sum_{e in eq*512..+512} Wg[g][e]*Winp[e][c]
        int t2 = bid - 3072;            // 0..15
        int cq = t2 & 3, eq = t2 >> 2;  // c-chunk(256), e-quarter(512)
        __shared__ float wg_l[8][512];
        #pragma unroll
        for (int i = 0; i < 16; ++i) {
            int idx = tid + i * 256;    // 0..4095
            wg_l[idx >> 9][idx & 511] = Wg[(size_t)(idx >> 9) * 2048 + eq * 512 + (idx & 511)];
        }
        __syncthreads();
        int c = cq * 256 + tid;
        float acc[8] = {};
        for (int e = 0; e < 512; ++e) {
            float v = Winp[(size_t)(eq * 512 + e) * 1024 + c];
            #pragma unroll
            for (int g = 0; g < 8; ++g) acc[g] += wg_l[g][e] * v;
        }
        #pragma unroll
        for (int g = 0; g < 8; ++g) wgp[(size_t)eq * 8192 + g * 1024 + c] = acc[g];
    } else {
        // cg[g] = Wg[g,:].b_inp + bg[g]  (8 groups x 32 lanes)
        int g = tid >> 5, sub = tid & 31;
        float t = 0.f;
        for (int e = sub; e < 2048; e += 32) t += Wg[(size_t)g * 2048 + e] * binp[e];
        #pragma unroll
        for (int m = 16; m; m >>= 1) t += __shfl_xor(t, m);
        if (sub == 0) cg[g] = t + bg[g];
    }
}

// ---------------- K2: bf16 MFMA GEMM (BT), 64x64 tile, BK=64, 4 waves (2x2), ring-2,
// counted vmcnt, both-sides chunk-XOR swizzle; 4 blocks/CU. (verbatim from R11, passed)
// MODE 0: f32 out (+split-K z). MODE 3: em1=exp(acc)-1 bf16 out + atomic column sums.
template <int MODE>
__global__ __launch_bounds__(256, 4) void k_mfma_gemm(
    const u16* __restrict__ A, const u16* __restrict__ B,
    float* __restrict__ Cf, u16* __restrict__ Cb,
    const float* __restrict__ agT, float* __restrict__ ssum, float* __restrict__ sagm,
    int Kld, int Kloop, int N,
    long long zA, long long zB, long long zC)
{
    constexpr int MR = 2, NR = 2;
    __shared__ u16 As[2][64 * 64];
    __shared__ u16 Bs[2][64 * 64];
    int bz = blockIdx.z;
    A += (size_t)bz * zA; B += (size_t)bz * zB;
    int tid = threadIdx.x, lane = tid & 63, wave = tid >> 6;
    int wr = wave >> 1, wc = wave & 1;
    int i0 = blockIdx.y * 64, j0 = blockIdx.x * 64;
    int fr = lane & 15, fg = lane >> 4;
    f32x4 acc[MR][NR] = {};

    int srcOff = ((tid & 7) ^ ((tid >> 3) & 7)) * 8;
    int srow = tid >> 3;

    auto stage = [&](int buf, int t) {
        int kt = t * 64;
        #pragma unroll
        for (int q = 0; q < 2; ++q)
            gload16(A + (size_t)(i0 + q * 32 + srow) * Kld + kt + srcOff,
                    &As[buf][(q * 256 + wave * 64) * 8]);
        #pragma unroll
        for (int q = 0; q < 2; ++q)
            gload16(B + (size_t)(j0 + q * 32 + srow) * Kld + kt + srcOff,
                    &Bs[buf][(q * 256 + wave * 64) * 8]);
    };
    auto compute = [&](int buf) {
        #pragma unroll
        for (int h = 0; h < 2; ++h) {
            bf16x8 af[MR], bv[NR];
            #pragma unroll
            for (int mi = 0; mi < MR; ++mi) {
                int row = wr * 32 + mi * 16 + fr;
                af[mi] = *(const bf16x8*)&As[buf][row * 64 + (((h * 4 + fg) ^ (fr & 7)) * 8)];
            }
            #pragma unroll
            for (int ni = 0; ni < NR; ++ni) {
                int row = wc * 32 + ni * 16 + fr;
                bv[ni] = *(const bf16x8*)&Bs[buf][row * 64 + (((h * 4 + fg) ^ (fr & 7)) * 8)];
            }
            #pragma unroll
            for (int mi = 0; mi < MR; ++mi)
                #pragma unroll
                for (int ni = 0; ni < NR; ++ni)
                    acc[mi][ni] = __builtin_amdgcn_mfma_f32_16x16x32_bf16(
                        af[mi], bv[ni], acc[mi][ni], 0, 0, 0);
        }
    };

    int nk = Kloop >> 6;
    stage(0, 0);
    int cur = 0;
    for (int t = 0; t < nk; ++t) {
        if (t + 1 < nk) {
            stage(cur ^ 1, t + 1);
            asm volatile("s_waitcnt vmcnt(4)" ::: "memory");
        } else {
            asm volatile("s_waitcnt vmcnt(0)" ::: "memory");
        }
        __builtin_amdgcn_s_barrier();
        __builtin_amdgcn_sched_barrier(0);
        compute(cur);
        __builtin_amdgcn_s_barrier();
        cur ^= 1;
    }

    if constexpr (MODE == 3) {
        int bcol = j0 >> 10;
        int g = i0 >> 7;
        float ag2[NR];
        #pragma unroll
        for (int ni = 0; ni < NR; ++ni) {
            int col = j0 + wc * 32 + ni * 16 + fr;
            ag2[ni] = agT[((size_t)bcol * 8 + g) * 1024 + (col & 1023)];
        }
        #pragma unroll
        for (int mi = 0; mi < MR; ++mi)
            #pragma unroll
            for (int r = 0; r < 4; ++r) {
                int row = i0 + wr * 32 + mi * 16 + fg * 4 + r;
                float es = 0.f, sa = 0.f;
                #pragma unroll
                for (int ni = 0; ni < NR; ++ni) {
                    int col = j0 + wc * 32 + ni * 16 + fr;
                    float e = expf(acc[mi][ni][r]);
                    es += e; sa += ag2[ni] * e;
                    Cb[(size_t)row * N + col] = f2bf(e - 1.f);
                }
                #pragma unroll
                for (int m = 8; m; m >>= 1) { es += __shfl_xor(es, m); sa += __shfl_xor(sa, m); }
                if (fr == 0) {
                    atomicAdd(&ssum[row * 4 + bcol], es);
                    atomicAdd(&sagm[row * 4 + bcol], sa);
                }
            }
    } else {
        float* C2 = Cf + (size_t)bz * zC;
        #pragma unroll
        for (int ni = 0; ni < NR; ++ni) {
            int col = j0 + wc * 32 + ni * 16 + fr;
            #pragma unroll
            for (int mi = 0; mi < MR; ++mi)
                #pragma unroll
                for (int r = 0; r < 4; ++r) {
                    int row = i0 + wr * 32 + mi * 16 + fg * 4 + r;
                    C2[(size_t)row * N + col] = acc[mi][ni][r];
                }
        }
    }
}

// ---------------- K_mid: wcred (1024) | agT from wgp partials (128) | zero ssum/sagm (1) ----------------
__global__ __launch_bounds__(256) void k_mid(const float* __restrict__ wcp,
                                             u16* __restrict__ wcb,
                                             const u16* __restrict__ xtn,
                                             const float* __restrict__ wgp,
                                             const float* __restrict__ cg,
                                             float* __restrict__ agT,
                                             float* __restrict__ zz) {
    int bid = blockIdx.x, tid = threadIdx.x;
    if (bid < 1024) {
        int i = (bid * 256 + tid) * 4;
        float4 a = *(const float4*)(wcp + i);
        float4 b = *(const float4*)(wcp + 1048576 + i);
        float4 c = *(const float4*)(wcp + 2097152 + i);
        float4 d = *(const float4*)(wcp + 3145728 + i);
        ushort4 o;
        o.x = f2bf(a.x + b.x + c.x + d.x);
        o.y = f2bf(a.y + b.y + c.y + d.y);
        o.z = f2bf(a.z + b.z + c.z + d.z);
        o.w = f2bf(a.w + b.w + c.w + d.w);
        *(ushort4*)(wcb + i) = o;
    } else if (bid < 1152) {
        // agT[b][g][m] = sigmoid(Wg_eff . xtn[b,m,:] + c_g), Wg_eff = sum of 4 wgp partials
        int t2 = bid - 1024;
        int b = t2 >> 5, ms = t2 & 31;
        int w = tid >> 6, lane = tid & 63;
        __shared__ float wgel[8192];
        __shared__ float cgl[8];
        #pragma unroll
        for (int i = 0; i < 8; ++i) {
            int idx = (tid + i * 256) * 4;
            float4 p0 = *(const float4*)&wgp[idx];
            float4 p1 = *(const float4*)&wgp[8192 + idx];
            float4 p2 = *(const float4*)&wgp[16384 + idx];
            float4 p3 = *(const float4*)&wgp[24576 + idx];
            float4 s;
            s.x = p0.x + p1.x + p2.x + p3.x;
            s.y = p0.y + p1.y + p2.y + p3.y;
            s.z = p0.z + p1.z + p2.z + p3.z;
            s.w = p0.w + p1.w + p2.w + p3.w;
            *(float4*)&wgel[idx] = s;
        }
        if (tid < 8) cgl[tid] = cg[tid];
        __syncthreads();
        for (int r = 0; r < 8; ++r) {
            int m = ms * 32 + w * 8 + r;
            const u16* xr = xtn + ((size_t)b * 1024 + m) * 1024;
            float acc[8] = {};
            #pragma unroll
            for (int i = 0; i < 2; ++i) {
                int c0 = i * 512 + lane * 8;
                bf16x8 hv = *(const bf16x8*)(xr + c0);
                float xf[8];
                #pragma unroll
                for (int j = 0; j < 8; ++j) xf[j] = bf2f((u16)hv[j]);
                #pragma unroll
                for (int g = 0; g < 8; ++g) {
                    float4 wa = *(const float4*)&wgel[g * 1024 + c0];
                    float4 wb = *(const float4*)&wgel[g * 1024 + c0 + 4];
                    acc[g] += xf[0] * wa.x + xf[1] * wa.y + xf[2] * wa.z + xf[3] * wa.w
                            + xf[4] * wb.x + xf[5] * wb.y + xf[6] * wb.z + xf[7] * wb.w;
                }
            }
            #pragma unroll
            for (int g = 0; g < 8; ++g)
                #pragma unroll
                for (int off = 32; off; off >>= 1) acc[g] += __shfl_xor(acc[g], off);
            if (lane < 8)
                agT[((size_t)b * 8 + lane) * 1024 + m] =
                    1.f / (1.f + expf(-(acc[lane] + cgl[lane])));
        }
    } else {
        // zero ssum+sagm (8192 floats) before the logits GEMM's atomics
        float4 z = make_float4(0.f, 0.f, 0.f, 0.f);
        #pragma unroll
        for (int i = 0; i < 8; ++i)
            *(float4*)&zz[(tid + i * 256) * 4] = z;
    }
}

// ---------------- K_wfx2: fused wf + wfx.  grid (ms 8, b 4, gh 2) ----------------
// wf[b,g,m] = ag[m]*(C0_g + sum_k c1[g,k]*em1[gk][m]), c1 = Wf/ssum; kept in LDS.
// wfxp[ms][b][g][c] = sum_{m in seg} wf[g,m]*xtn[b,m,c].  Also u (ms==0).
__global__ __launch_bounds__(256) void k_wfx2(const u16* __restrict__ em1,
                                              const float* __restrict__ ssum,
                                              const float* __restrict__ sagm,
                                              const float* __restrict__ Wf,
                                              const float* __restrict__ agT,
                                              const u16* __restrict__ xtn,
                                              float* __restrict__ wfxp,
                                              float* __restrict__ u) {
    int ms = blockIdx.x, b = blockIdx.y, gh = blockIdx.z;
    int tid = threadIdx.x;
    int g0 = gh * 4;
    __shared__ float c1[512];
    __shared__ float C0[4];
    __shared__ float wf_l[4][128];
    #pragma unroll
    for (int i = 0; i < 2; ++i) {
        int kk = tid + i * 256;              // 0..511
        int gk = g0 * 128 + kk;
        float cv = Wf[gk & 127] / ssum[gk * 4 + b];
        c1[kk] = cv;
        if (ms == 0) u[(size_t)b * 1024 + gk] = cv * sagm[gk * 4 + b];
    }
    __syncthreads();
    {
        int w = tid >> 6, l = tid & 63;
        float s = c1[w * 128 + l] + c1[w * 128 + 64 + l];
        #pragma unroll
        for (int m = 32; m; m >>= 1) s += __shfl_xor(s, m);
        if (l == 0) C0[w] = s;
    }
    __syncthreads();
    {
        int w = tid >> 6, l = tid & 63;
        int g = g0 + w;
        float a0 = 0.f, a1 = 0.f;
        const u16* base = em1 + (size_t)(g * 128) * 4096 + b * 1024 + ms * 128 + 2 * l;
        for (int k = 0; k < 128; ++k) {
            unsigned pr = *(const unsigned*)(base + (size_t)k * 4096);
            float cv = c1[w * 128 + k];
            a0 += cv * bf2f((u16)(pr & 0xffff));
            a1 += cv * bf2f((u16)(pr >> 16));
        }
        float c0v = C0[w];
        const float* agp = agT + ((size_t)b * 8 + g) * 1024 + ms * 128;
        wf_l[w][2 * l]     = (c0v + a0) * agp[2 * l];
        wf_l[w][2 * l + 1] = (c0v + a1) * agp[2 * l + 1];
    }
    __syncthreads();
    #pragma unroll
    for (int cs = 0; cs < 4; ++cs) {
        int c = cs * 256 + tid;
        float acc[4] = {};
        const u16* xb = xtn + ((size_t)b * 1024 + ms * 128) * 1024 + c;
        for (int m = 0; m < 128; ++m) {
            float xv = bf2f(xb[(size_t)m * 1024]);
            #pragma unroll
            for (int lg = 0; lg < 4; ++lg) acc[lg] += wf_l[lg][m] * xv;
        }
        #pragma unroll
        for (int lg = 0; lg < 4; ++lg)
            wfxp[(((size_t)ms * 4 + b) * 8 + g0 + lg) * 1024 + c] = acc[lg];
    }
}

// ---------------- K_vfpart: cs<8: vf += wfx . W_inp^T slice; cs==8: -u.cent + sw*b_inp ----------------
__global__ __launch_bounds__(256) void k_vfpart(const float* __restrict__ wfxp,
                                                const u16* __restrict__ winpT,
                                                const float* __restrict__ u,
                                                const float* __restrict__ cent,
                                                const float* __restrict__ binp,
                                                float* __restrict__ vfp) {
    int g = blockIdx.x, cs = blockIdx.y;  // (8, 9)
    int tid = threadIdx.x;
    if (cs < 8) {
        __shared__ float wfx_l[4][128];
        #pragma unroll
        for (int i = 0; i < 2; ++i) {
            int idx = tid + i * 256;
            int bb = idx >> 7, c2 = idx & 127;
            float s = 0.f;
            #pragma unroll
            for (int msq = 0; msq < 8; ++msq)
                s += wfxp[(((size_t)msq * 4 + bb) * 8 + g) * 1024 + cs * 128 + c2];
            wfx_l[bb][c2] = s;
        }
        __syncthreads();
        int d = tid;
        float acc[4] = {};
        for (int c2 = 0; c2 < 128; ++c2) {
            float wv = bf2f(winpT[(size_t)(cs * 128 + c2) * 2048 + g * 256 + d]);
            #pragma unroll
            for (int bb = 0; bb < 4; ++bb) acc[bb] += wfx_l[bb][c2] * wv;
        }
        #pragma unroll
        for (int bb = 0; bb < 4; ++bb)
            vfp[(((size_t)bb * 8 + g) * 9 + cs) * 256 + d] = acc[bb];
    } else {
        __shared__ float ul[4][128];
        __shared__ float swl[4];
        #pragma unroll
        for (int i = 0; i < 2; ++i) {
            int idx = tid + i * 256;
            ul[idx >> 7][idx & 127] = u[((size_t)(idx >> 7) * 8 + g) * 128 + (idx & 127)];
        }
        __syncthreads();
        if (tid < 4) {
            float s = 0.f;
            for (int k = 0; k < 128; ++k) s += ul[tid][k];
            swl[tid] = s;
        }
        __syncthreads();
        int d = tid;
        float acc[4] = {};
        for (int k = 0; k < 128; ++k) {
            float cv = cent[k * 256 + d];
            #pragma unroll
            for (int bb = 0; bb < 4; ++bb) acc[bb] -= ul[bb][k] * cv;
        }
        float bi = binp[g * 256 + d];
        #pragma unroll
        for (int bb = 0; bb < 4; ++bb)
            vfp[(((size_t)bb * 8 + g) * 9 + 8) * 256 + d] = acc[bb] + swl[bb] * bi;
    }
}

// ---------------- K_fin: finalize vf -> rank-8 NS -> COALESCED triuvec. grid (8 slices, 4 b) ----------------
#define MM8(DST, P, Q) do { if (act) { float s_ = 0.f; \
    _Pragma("unroll") \
    for (int l_ = 0; l_ < 8; ++l_) s_ += P[ii][l_] * Q[l_][jj]; \
    DST[ii][jj] = s_; } __syncthreads(); } while (0)

__global__ __launch_bounds__(256) void k_fin(const float* __restrict__ vfp,
                                             const float* __restrict__ bf,
                                             float* __restrict__ out) {
    int slice = blockIdx.x, b = blockIdx.y;
    int tid = threadIdx.x, d = tid;
    __shared__ float Vl[256][9];
    __shared__ float4 Vl4a[256], Vl4b[256];
    __shared__ float Wr_l[256][8];
    __shared__ float red[256];
    __shared__ float Sp[4][64];
    __shared__ float Sm[8][8], W1[8][8], W2[8][8], YmL[8][8], ZmL[8][8], ZYL[8][8], FmL[8][8];
    float bfv = bf[0];
    float vfl[8];
    #pragma unroll
    for (int g = 0; g < 8; ++g) {
        float acc = 0.f;
        for (int mc = 0; mc < 9; ++mc)
            acc += vfp[(((size_t)b * 8 + g) * 9 + mc) * 256 + d];
        vfl[g] = acc + bfv;
    }
    float mean = 0.f;
    #pragma unroll
    for (int g = 0; g < 8; ++g) mean += vfl[g];
    mean *= 0.125f;
    float trp = 0.f;
    #pragma unroll
    for (int g = 0; g < 8; ++g) { float v = vfl[g] - mean; Vl[d][g] = v; vfl[g] = v; trp += v * v; }
    Vl4a[d] = make_float4(vfl[0], vfl[1], vfl[2], vfl[3]);
    Vl4b[d] = make_float4(vfl[4], vfl[5], vfl[6], vfl[7]);
    red[tid] = trp;
    __syncthreads();
    for (int s = 128; s > 0; s >>= 1) { if (tid < s) red[tid] += red[tid + s]; __syncthreads(); }
    float tr = red[0] * 0.125f;  // trace(cov)
    {
        int q = tid >> 6, l = tid & 63;
        int si = l >> 3, sj = l & 7;
        float sv = 0.f;
        for (int dd = q * 64; dd < q * 64 + 64; ++dd) sv += Vl[dd][si] * Vl[dd][sj];
        Sp[q][l] = sv;
    }
    __syncthreads();
    bool act = tid < 64;
    int ii = (tid >> 3) & 7, jj = tid & 7;
    if (act) Sm[ii][jj] = (Sp[0][tid] + Sp[1][tid] + Sp[2][tid] + Sp[3][tid]) / (8.f * tr);
    __syncthreads();
    if (act) {
        YmL[ii][jj] = (ii == jj ? 1.5f : 0.f) - 0.5f * Sm[ii][jj];
        ZmL[ii][jj] = (ii == jj ? -0.5f : 0.f);
    }
    __syncthreads();
    float ya = 0.f, za = 1.5f;
    MM8(W1, Sm, YmL);
    MM8(W2, ZmL, W1);
    float pa = za * ya;
    if (act) ZYL[ii][jj] = -0.5f * (za * YmL[ii][jj] + ya * ZmL[ii][jj] + W2[ii][jj]);
    __syncthreads();
    float zya = 1.5f - 0.5f * pa;
    MM8(W1, Sm, ZYL);
    MM8(W2, YmL, W1);
    if (act) YmL[ii][jj] = ya * ZYL[ii][jj] + zya * YmL[ii][jj] + W2[ii][jj];
    __syncthreads();
    ya = ya * zya;
    MM8(W1, Sm, ZmL);
    MM8(W2, ZYL, W1);
    if (act) ZmL[ii][jj] = zya * ZmL[ii][jj] + za * ZYL[ii][jj] + W2[ii][jj];
    __syncthreads();
    za = zya * za;
    MM8(W1, Sm, YmL);
    MM8(W2, ZmL, W1);
    float p2a = za * ya;
    if (act) ZYL[ii][jj] = za * YmL[ii][jj] + ya * ZmL[ii][jj] + W2[ii][jj];
    __syncthreads();
    MM8(W1, Sm, ZYL);
    MM8(W2, YmL, W1);
    if (act) FmL[ii][jj] = 0.5f * ((3.f - p2a) * YmL[ii][jj] - ya * ZYL[ii][jj] - W2[ii][jj]);
    __syncthreads();
    float fa = 0.5f * ya * (3.f - p2a);
    float sqtr = sqrtf(tr);
    float scaleF = 1.f / (8.f * sqtr);
    #pragma unroll
    for (int jo = 0; jo < 8; ++jo) {
        float sv = 0.f;
        #pragma unroll
        for (int i = 0; i < 8; ++i) sv += vfl[i] * FmL[i][jo];
        Wr_l[d][jo] = sv * scaleF;
    }
    float s0v = fa * sqtr;
    __syncthreads();
    // coalesced triuvec: row dd, lanes e>=dd write consecutive addresses
    int dd0 = slice * 32;
    for (int dd = dd0; dd < dd0 + 32; ++dd) {
        int e = tid;
        if (e >= dd) {
            float w0 = Wr_l[dd][0], w1 = Wr_l[dd][1], w2 = Wr_l[dd][2], w3 = Wr_l[dd][3];
            float w4 = Wr_l[dd][4], w5 = Wr_l[dd][5], w6 = Wr_l[dd][6], w7 = Wr_l[dd][7];
            float4 va = Vl4a[e], vb = Vl4b[e];
            float v = w0 * va.x + w1 * va.y + w2 * va.z + w3 * va.w
                    + w4 * vb.x + w5 * vb.y + w6 * vb.z + w7 * vb.w;
            if (e == dd) v += s0v;
            size_t base = (size_t)b * 32896 + (size_t)dd * 256 - ((size_t)dd * (dd - 1)) / 2;
            out[base + (e - dd)] = v;
        }
    }
}

extern "C" void kernel_launch(void* const* d_in, const int* in_sizes, int n_in,
                              void* d_out, int out_size, void* d_ws, size_t ws_size,
                              hipStream_t stream) {
    const float* x    = (const float*)d_in[0];
    const float* cent = (const float*)d_in[1];
    const float* Winp = (const float*)d_in[2];
    const float* binp = (const float*)d_in[3];
    const float* Wg   = (const float*)d_in[4];
    const float* bg   = (const float*)d_in[5];
    const float* Wgk  = (const float*)d_in[6];
    const float* Wf   = (const float*)d_in[8];
    const float* bf   = (const float*)d_in[9];
    float* out = (float*)d_out;
    char* wsb = (char*)d_ws;

    // byte-offset workspace layout
    u16*   xtnb  = (u16*)(wsb);                          // [4096][1024] bf16, 8 MB
    u16*   ltb   = (u16*)(wsb + (8ull << 20));           // em1 [1024][4096] bf16, 8 MB
    u16*   wgkb  = (u16*)(wsb + (16ull << 20));          // [1024][2048] bf16, 4 MB
    u16*   winpT = (u16*)(wsb + (20ull << 20));          // [1024][2048] bf16, 4 MB
    float* wcp   = (float*)(wsb + (24ull << 20));        // [4][1024][1024] f32, 16 MB
    u16*   wcb   = (u16*)(wsb + (40ull << 20));          // [1024][1024] bf16, 2 MB
    float* misc  = (float*)(wsb + (42ull << 20));
    float* wgp   = misc;                 // [4][8][1024] partials (plain stores)
    float* cg    = wgp + 32768;          // [8]
    float* ssum  = cg + 8;               // [1024][4]  (zeroed by k_mid, atomics in logits)
    float* sagm  = ssum + 4096;          // [1024][4]
    float* agT   = sagm + 4096;          // [4][8][1024]
    float* u     = agT + 32768;          // [32][128] -> stored as [4][1024]
    float* wfxp  = u + 4096;             // [8][4][8][1024]
    float* vfp   = wfxp + 262144;        // [4][8][9][256]

    k_pre<<<3089, 256, 0, stream>>>(x, Wgk, Winp, Wg, binp, bg, xtnb, wgkb, winpT, wgp, cg);
    // Wc = W_gk @ W_inp: M=1024, N=1024, K=2048 split-K (4 x 512), 64x64 tile -> 1024 blocks (4/CU)
    k_mfma_gemm<0><<<dim3(16, 16, 4), 256, 0, stream>>>(
        wgkb, winpT, wcp, nullptr, nullptr, nullptr, nullptr,
        2048, 512, 1024, 512LL, 512LL, 1048576LL);
    k_mid<<<1153, 256, 0, stream>>>(wcp, wcb, xtnb, wgp, cg, agT, ssum);
    // logits: em1[gk][b*1024+m] = exp(Wc @ xtn^T) - 1 (bf16) + atomic ssum/sagm
    k_mfma_gemm<3><<<dim3(64, 16, 1), 256, 0, stream>>>(
        wcb, xtnb, nullptr, ltb, agT, ssum, sagm,
        1024, 1024, 4096, 0, 0, 0);
    k_wfx2<<<dim3(8, 4, 2), 256, 0, stream>>>(ltb, ssum, sagm, Wf, agT, xtnb, wfxp, u);
    k_vfpart<<<dim3(8, 9), 256, 0, stream>>>(wfxp, winpT, u, cent, binp, vfp);
    k_fin<<<dim3(8, 4), 256, 0, stream>>>(vfp, bf, out);
}

// Round 13
// 178.094 us; speedup vs baseline: 1.0854x; 1.0854x over previous
//
#include <hip/hip_runtime.h>
#include <math.h>

typedef float f32x4 __attribute__((ext_vector_type(4)));
typedef short bf16x8 __attribute__((ext_vector_type(8)));
typedef unsigned short u16;

__device__ __forceinline__ u16 f2bf(float f) {
    unsigned u = __builtin_bit_cast(unsigned, f);
    u += 0x7fff + ((u >> 16) & 1);   // RNE
    return (u16)(u >> 16);
}
__device__ __forceinline__ float bf2f(u16 s) {
    unsigned v = ((unsigned)s) << 16;
    return __builtin_bit_cast(float, v);
}
__device__ __forceinline__ void gload16(const void* g, void* l) {
    __builtin_amdgcn_global_load_lds(
        (const __attribute__((address_space(1))) unsigned int*)g,
        (__attribute__((address_space(3))) unsigned int*)l, 16, 0, 0);
}

// ---------------- K_pre: transpose_norm (512) | f2bf Wgk (2048) | Winp^T (512)
//                  | wgp partials (32) | cg (1)
// LDS: all branch arrays OVERLAID on one 33KB buffer (branches are mutually exclusive)
// -> 4 blocks/CU instead of 2 (R12 bug: summed allocations = 65KB).
__global__ __launch_bounds__(256) void k_pre(const float* __restrict__ x,
                                             const float* __restrict__ Wgk,
                                             const float* __restrict__ Winp,
                                             const float* __restrict__ Wg,
                                             const float* __restrict__ binp,
                                             const float* __restrict__ bg,
                                             u16* __restrict__ xtn,
                                             u16* __restrict__ wgkb,
                                             u16* __restrict__ winpT,
                                             float* __restrict__ wgp,
                                             float* __restrict__ cg) {
    __shared__ __align__(16) char smraw[8 * 1032 * 4 + 64];   // 33 KB overlay
    int bid = blockIdx.x, tid = threadIdx.x;
    if (bid < 512) {
        // x [32,1024,16,8] -> xtn[b][m][c] bf16, L2-normalized over c
        float (*tile)[1032] = reinterpret_cast<float(*)[1032]>(smraw);
        float* inv = reinterpret_cast<float*>(smraw + 8 * 1032 * 4);
        int b8 = bid >> 4, hh = bid & 15;
        const float* src = x + (size_t)b8 * 1024 * 128 + hh * 8;
        #pragma unroll
        for (int r = 0; r < 4; ++r) {
            int c = tid * 4 + r;
            const float* p = src + (size_t)c * 128;
            float4 v0 = *(const float4*)(p);
            float4 v1 = *(const float4*)(p + 4);
            tile[0][c] = v0.x; tile[1][c] = v0.y; tile[2][c] = v0.z; tile[3][c] = v0.w;
            tile[4][c] = v1.x; tile[5][c] = v1.y; tile[6][c] = v1.z; tile[7][c] = v1.w;
        }
        __syncthreads();
        int w = tid >> 5, j = tid & 31;
        float s = 0.f;
        #pragma unroll 8
        for (int i = 0; i < 32; ++i) { float v = tile[w][i * 32 + j]; s += v * v; }
        #pragma unroll
        for (int m = 16; m; m >>= 1) s += __shfl_xor(s, m);
        if (j == 0) inv[w] = 1.0f / fmaxf(sqrtf(s), 1e-12f);
        __syncthreads();
        int b = b8 >> 3, t = b8 & 7;
        int c0 = tid * 4;
        for (int w2 = 0; w2 < 8; ++w2) {
            int m = t * 128 + hh * 8 + w2;
            float sc = inv[w2];
            u16* dst = xtn + ((size_t)b * 1024 + m) * 1024;
            ushort4 o;
            o.x = f2bf(tile[w2][c0 + 0] * sc);
            o.y = f2bf(tile[w2][c0 + 1] * sc);
            o.z = f2bf(tile[w2][c0 + 2] * sc);
            o.w = f2bf(tile[w2][c0 + 3] * sc);
            *(ushort4*)(dst + c0) = o;
        }
    } else if (bid < 2560) {
        int i = ((bid - 512) * 256 + tid) * 4;
        float4 v = *(const float4*)(Wgk + i);
        ushort4 o;
        o.x = f2bf(v.x); o.y = f2bf(v.y); o.z = f2bf(v.z); o.w = f2bf(v.w);
        *(ushort4*)(wgkb + i) = o;
    } else if (bid < 3072) {
        float (*tile)[65] = reinterpret_cast<float(*)[65]>(smraw);   // 16.6 KB of overlay
        int tb = bid - 2560;            // 0..511
        int er = tb & 31, cr = tb >> 5; // e-tile(64), c-tile(64)
        #pragma unroll
        for (int i = 0; i < 16; ++i) {
            int idx = tid + i * 256;
            int r = idx >> 6, c = idx & 63;
            tile[r][c] = Winp[(size_t)(er * 64 + r) * 1024 + cr * 64 + c];
        }
        __syncthreads();
        #pragma unroll
        for (int i = 0; i < 16; ++i) {
            int idx = tid + i * 256;
            int cc = idx >> 6, rr = idx & 63;
            winpT[(size_t)(cr * 64 + cc) * 2048 + er * 64 + rr] = f2bf(tile[rr][cc]);
        }
    } else if (bid < 3104) {
        // wgp[eq][g][c] = sum_{e in eq*256..+256} Wg[g][e]*Winp[e][c]   (32 blocks)
        float (*wg_l)[256] = reinterpret_cast<float(*)[256]>(smraw);   // 8 KB of overlay
        int t2 = bid - 3072;            // 0..31
        int cq = t2 & 3, eq = t2 >> 2;  // c-chunk(256), e-octant(256)
        #pragma unroll
        for (int i = 0; i < 8; ++i) {
            int idx = tid + i * 256;    // 0..2047
            wg_l[idx >> 8][idx & 255] = Wg[(size_t)(idx >> 8) * 2048 + eq * 256 + (idx & 255)];
        }
        __syncthreads();
        int c = cq * 256 + tid;
        float acc[8] = {};
        #pragma unroll 2
        for (int e = 0; e < 256; ++e) {
            float v = Winp[(size_t)(eq * 256 + e) * 1024 + c];
            #pragma unroll
            for (int g = 0; g < 8; ++g) acc[g] += wg_l[g][e] * v;
        }
        #pragma unroll
        for (int g = 0; g < 8; ++g) wgp[(size_t)eq * 8192 + g * 1024 + c] = acc[g];
    } else {
        // cg[g] = Wg[g,:].b_inp + bg[g]  (8 groups x 32 lanes)
        int g = tid >> 5, sub = tid & 31;
        float t = 0.f;
        for (int e = sub; e < 2048; e += 32) t += Wg[(size_t)g * 2048 + e] * binp[e];
        #pragma unroll
        for (int m = 16; m; m >>= 1) t += __shfl_xor(t, m);
        if (sub == 0) cg[g] = t + bg[g];
    }
}

// ---------------- K2: bf16 MFMA GEMM (BT), 64x64 tile, BK=64, 4 waves (2x2), ring-2,
// counted vmcnt, both-sides chunk-XOR swizzle; 4 blocks/CU. (verbatim, passed R11/R12)
// MODE 0: f32 out (+split-K z). MODE 3: em1=exp(acc)-1 bf16 out + atomic column sums.
template <int MODE>
__global__ __launch_bounds__(256, 4) void k_mfma_gemm(
    const u16* __restrict__ A, const u16* __restrict__ B,
    float* __restrict__ Cf, u16* __restrict__ Cb,
    const float* __restrict__ agT, float* __restrict__ ssum, float* __restrict__ sagm,
    int Kld, int Kloop, int N,
    long long zA, long long zB, long long zC)
{
    constexpr int MR = 2, NR = 2;
    __shared__ u16 As[2][64 * 64];
    __shared__ u16 Bs[2][64 * 64];
    int bz = blockIdx.z;
    A += (size_t)bz * zA; B += (size_t)bz * zB;
    int tid = threadIdx.x, lane = tid & 63, wave = tid >> 6;
    int wr = wave >> 1, wc = wave & 1;
    int i0 = blockIdx.y * 64, j0 = blockIdx.x * 64;
    int fr = lane & 15, fg = lane >> 4;
    f32x4 acc[MR][NR] = {};

    int srcOff = ((tid & 7) ^ ((tid >> 3) & 7)) * 8;
    int srow = tid >> 3;

    auto stage = [&](int buf, int t) {
        int kt = t * 64;
        #pragma unroll
        for (int q = 0; q < 2; ++q)
            gload16(A + (size_t)(i0 + q * 32 + srow) * Kld + kt + srcOff,
                    &As[buf][(q * 256 + wave * 64) * 8]);
        #pragma unroll
        for (int q = 0; q < 2; ++q)
            gload16(B + (size_t)(j0 + q * 32 + srow) * Kld + kt + srcOff,
                    &Bs[buf][(q * 256 + wave * 64) * 8]);
    };
    auto compute = [&](int buf) {
        #pragma unroll
        for (int h = 0; h < 2; ++h) {
            bf16x8 af[MR], bv[NR];
            #pragma unroll
            for (int mi = 0; mi < MR; ++mi) {
                int row = wr * 32 + mi * 16 + fr;
                af[mi] = *(const bf16x8*)&As[buf][row * 64 + (((h * 4 + fg) ^ (fr & 7)) * 8)];
            }
            #pragma unroll
            for (int ni = 0; ni < NR; ++ni) {
                int row = wc * 32 + ni * 16 + fr;
                bv[ni] = *(const bf16x8*)&Bs[buf][row * 64 + (((h * 4 + fg) ^ (fr & 7)) * 8)];
            }
            #pragma unroll
            for (int mi = 0; mi < MR; ++mi)
                #pragma unroll
                for (int ni = 0; ni < NR; ++ni)
                    acc[mi][ni] = __builtin_amdgcn_mfma_f32_16x16x32_bf16(
                        af[mi], bv[ni], acc[mi][ni], 0, 0, 0);
        }
    };

    int nk = Kloop >> 6;
    stage(0, 0);
    int cur = 0;
    for (int t = 0; t < nk; ++t) {
        if (t + 1 < nk) {
            stage(cur ^ 1, t + 1);
            asm volatile("s_waitcnt vmcnt(4)" ::: "memory");
        } else {
            asm volatile("s_waitcnt vmcnt(0)" ::: "memory");
        }
        __builtin_amdgcn_s_barrier();
        __builtin_amdgcn_sched_barrier(0);
        compute(cur);
        __builtin_amdgcn_s_barrier();
        cur ^= 1;
    }

    if constexpr (MODE == 3) {
        int bcol = j0 >> 10;
        int g = i0 >> 7;
        float ag2[NR];
        #pragma unroll
        for (int ni = 0; ni < NR; ++ni) {
            int col = j0 + wc * 32 + ni * 16 + fr;
            ag2[ni] = agT[((size_t)bcol * 8 + g) * 1024 + (col & 1023)];
        }
        #pragma unroll
        for (int mi = 0; mi < MR; ++mi)
            #pragma unroll
            for (int r = 0; r < 4; ++r) {
                int row = i0 + wr * 32 + mi * 16 + fg * 4 + r;
                float es = 0.f, sa = 0.f;
                #pragma unroll
                for (int ni = 0; ni < NR; ++ni) {
                    int col = j0 + wc * 32 + ni * 16 + fr;
                    float e = expf(acc[mi][ni][r]);
                    es += e; sa += ag2[ni] * e;
                    Cb[(size_t)row * N + col] = f2bf(e - 1.f);
                }
                #pragma unroll
                for (int m = 8; m; m >>= 1) { es += __shfl_xor(es, m); sa += __shfl_xor(sa, m); }
                if (fr == 0) {
                    atomicAdd(&ssum[row * 4 + bcol], es);
                    atomicAdd(&sagm[row * 4 + bcol], sa);
                }
            }
    } else {
        float* C2 = Cf + (size_t)bz * zC;
        #pragma unroll
        for (int ni = 0; ni < NR; ++ni) {
            int col = j0 + wc * 32 + ni * 16 + fr;
            #pragma unroll
            for (int mi = 0; mi < MR; ++mi)
                #pragma unroll
                for (int r = 0; r < 4; ++r) {
                    int row = i0 + wr * 32 + mi * 16 + fg * 4 + r;
                    C2[(size_t)row * N + col] = acc[mi][ni][r];
                }
        }
    }
}

// ---------------- K_mid: wcred (1024) | agT from 8 wgp partials (128) | zero ssum/sagm (1) ----------------
__global__ __launch_bounds__(256) void k_mid(const float* __restrict__ wcp,
                                             u16* __restrict__ wcb,
                                             const u16* __restrict__ xtn,
                                             const float* __restrict__ wgp,
                                             const float* __restrict__ cg,
                                             float* __restrict__ agT,
                                             float* __restrict__ zz) {
    int bid = blockIdx.x, tid = threadIdx.x;
    if (bid < 1024) {
        int i = (bid * 256 + tid) * 4;
        float4 a = *(const float4*)(wcp + i);
        float4 b = *(const float4*)(wcp + 1048576 + i);
        float4 c = *(const float4*)(wcp + 2097152 + i);
        float4 d = *(const float4*)(wcp + 3145728 + i);
        ushort4 o;
        o.x = f2bf(a.x + b.x + c.x + d.x);
        o.y = f2bf(a.y + b.y + c.y + d.y);
        o.z = f2bf(a.z + b.z + c.z + d.z);
        o.w = f2bf(a.w + b.w + c.w + d.w);
        *(ushort4*)(wcb + i) = o;
    } else if (bid < 1152) {
        // agT[b][g][m] = sigmoid(Wg_eff . xtn[b,m,:] + c_g), Wg_eff = sum of 8 wgp partials
        // (wgp = 256 KB -> L2-resident; re-sum per block is ~free)
        int t2 = bid - 1024;
        int b = t2 >> 5, ms = t2 & 31;
        int w = tid >> 6, lane = tid & 63;
        __shared__ float wgel[8192];
        __shared__ float cgl[8];
        #pragma unroll
        for (int i = 0; i < 8; ++i) {
            int idx = (tid + i * 256) * 4;
            float4 s = *(const float4*)&wgp[idx];
            #pragma unroll
            for (int eq = 1; eq < 8; ++eq) {
                float4 p = *(const float4*)&wgp[(size_t)eq * 8192 + idx];
                s.x += p.x; s.y += p.y; s.z += p.z; s.w += p.w;
            }
            *(float4*)&wgel[idx] = s;
        }
        if (tid < 8) cgl[tid] = cg[tid];
        __syncthreads();
        for (int r = 0; r < 8; ++r) {
            int m = ms * 32 + w * 8 + r;
            const u16* xr = xtn + ((size_t)b * 1024 + m) * 1024;
            float acc[8] = {};
            #pragma unroll
            for (int i = 0; i < 2; ++i) {
                int c0 = i * 512 + lane * 8;
                bf16x8 hv = *(const bf16x8*)(xr + c0);
                float xf[8];
                #pragma unroll
                for (int j = 0; j < 8; ++j) xf[j] = bf2f((u16)hv[j]);
                #pragma unroll
                for (int g = 0; g < 8; ++g) {
                    float4 wa = *(const float4*)&wgel[g * 1024 + c0];
                    float4 wb = *(const float4*)&wgel[g * 1024 + c0 + 4];
                    acc[g] += xf[0] * wa.x + xf[1] * wa.y + xf[2] * wa.z + xf[3] * wa.w
                            + xf[4] * wb.x + xf[5] * wb.y + xf[6] * wb.z + xf[7] * wb.w;
                }
            }
            #pragma unroll
            for (int g = 0; g < 8; ++g)
                #pragma unroll
                for (int off = 32; off; off >>= 1) acc[g] += __shfl_xor(acc[g], off);
            if (lane < 8)
                agT[((size_t)b * 8 + lane) * 1024 + m] =
                    1.f / (1.f + expf(-(acc[lane] + cgl[lane])));
        }
    } else {
        // zero ssum+sagm (8192 floats) before the logits GEMM's atomics
        float4 z = make_float4(0.f, 0.f, 0.f, 0.f);
        #pragma unroll
        for (int i = 0; i < 8; ++i)
            *(float4*)&zz[(tid + i * 256) * 4] = z;
    }
}

// ---------------- K_wfx2: fused wf + wfx.  grid (ms 8, b 4, gh 2)  (verbatim R12, passed) ----------------
__global__ __launch_bounds__(256) void k_wfx2(const u16* __restrict__ em1,
                                              const float* __restrict__ ssum,
                                              const float* __restrict__ sagm,
                                              const float* __restrict__ Wf,
                                              const float* __restrict__ agT,
                                              const u16* __restrict__ xtn,
                                              float* __restrict__ wfxp,
                                              float* __restrict__ u) {
    int ms = blockIdx.x, b = blockIdx.y, gh = blockIdx.z;
    int tid = threadIdx.x;
    int g0 = gh * 4;
    __shared__ float c1[512];
    __shared__ float C0[4];
    __shared__ float wf_l[4][128];
    #pragma unroll
    for (int i = 0; i < 2; ++i) {
        int kk = tid + i * 256;              // 0..511
        int gk = g0 * 128 + kk;
        float cv = Wf[gk & 127] / ssum[gk * 4 + b];
        c1[kk] = cv;
        if (ms == 0) u[(size_t)b * 1024 + gk] = cv * sagm[gk * 4 + b];
    }
    __syncthreads();
    {
        int w = tid >> 6, l = tid & 63;
        float s = c1[w * 128 + l] + c1[w * 128 + 64 + l];
        #pragma unroll
        for (int m = 32; m; m >>= 1) s += __shfl_xor(s, m);
        if (l == 0) C0[w] = s;
    }
    __syncthreads();
    {
        int w = tid >> 6, l = tid & 63;
        int g = g0 + w;
        float a0 = 0.f, a1 = 0.f;
        const u16* base = em1 + (size_t)(g * 128) * 4096 + b * 1024 + ms * 128 + 2 * l;
        for (int k = 0; k < 128; ++k) {
            unsigned pr = *(const unsigned*)(base + (size_t)k * 4096);
            float cv = c1[w * 128 + k];
            a0 += cv * bf2f((u16)(pr & 0xffff));
            a1 += cv * bf2f((u16)(pr >> 16));
        }
        float c0v = C0[w];
        const float* agp = agT + ((size_t)b * 8 + g) * 1024 + ms * 128;
        wf_l[w][2 * l]     = (c0v + a0) * agp[2 * l];
        wf_l[w][2 * l + 1] = (c0v + a1) * agp[2 * l + 1];
    }
    __syncthreads();
    #pragma unroll
    for (int cs = 0; cs < 4; ++cs) {
        int c = cs * 256 + tid;
        float acc[4] = {};
        const u16* xb = xtn + ((size_t)b * 1024 + ms * 128) * 1024 + c;
        for (int m = 0; m < 128; ++m) {
            float xv = bf2f(xb[(size_t)m * 1024]);
            #pragma unroll
            for (int lg = 0; lg < 4; ++lg) acc[lg] += wf_l[lg][m] * xv;
        }
        #pragma unroll
        for (int lg = 0; lg < 4; ++lg)
            wfxp[(((size_t)ms * 4 + b) * 8 + g0 + lg) * 1024 + c] = acc[lg];
    }
}

// ---------------- K_vfpart (verbatim R12, passed) ----------------
__global__ __launch_bounds__(256) void k_vfpart(const float* __restrict__ wfxp,
                                                const u16* __restrict__ winpT,
                                                const float* __restrict__ u,
                                                const float* __restrict__ cent,
                                                const float* __restrict__ binp,
                                                float* __restrict__ vfp) {
    int g = blockIdx.x, cs = blockIdx.y;  // (8, 9)
    int tid = threadIdx.x;
    if (cs < 8) {
        __shared__ float wfx_l[4][128];
        #pragma unroll
        for (int i = 0; i < 2; ++i) {
            int idx = tid + i * 256;
            int bb = idx >> 7, c2 = idx & 127;
            float s = 0.f;
            #pragma unroll
            for (int msq = 0; msq < 8; ++msq)
                s += wfxp[(((size_t)msq * 4 + bb) * 8 + g) * 1024 + cs * 128 + c2];
            wfx_l[bb][c2] = s;
        }
        __syncthreads();
        int d = tid;
        float acc[4] = {};
        for (int c2 = 0; c2 < 128; ++c2) {
            float wv = bf2f(winpT[(size_t)(cs * 128 + c2) * 2048 + g * 256 + d]);
            #pragma unroll
            for (int bb = 0; bb < 4; ++bb) acc[bb] += wfx_l[bb][c2] * wv;
        }
        #pragma unroll
        for (int bb = 0; bb < 4; ++bb)
            vfp[(((size_t)bb * 8 + g) * 9 + cs) * 256 + d] = acc[bb];
    } else {
        __shared__ float ul[4][128];
        __shared__ float swl[4];
        #pragma unroll
        for (int i = 0; i < 2; ++i) {
            int idx = tid + i * 256;
            ul[idx >> 7][idx & 127] = u[((size_t)(idx >> 7) * 8 + g) * 128 + (idx & 127)];
        }
        __syncthreads();
        if (tid < 4) {
            float s = 0.f;
            for (int k = 0; k < 128; ++k) s += ul[tid][k];
            swl[tid] = s;
        }
        __syncthreads();
        int d = tid;
        float acc[4] = {};
        for (int k = 0; k < 128; ++k) {
            float cv = cent[k * 256 + d];
            #pragma unroll
            for (int bb = 0; bb < 4; ++bb) acc[bb] -= ul[bb][k] * cv;
        }
        float bi = binp[g * 256 + d];
        #pragma unroll
        for (int bb = 0; bb < 4; ++bb)
            vfp[(((size_t)bb * 8 + g) * 9 + 8) * 256 + d] = acc[bb] + swl[bb] * bi;
    }
}

// ---------------- K_fin: finalize vf -> rank-8 NS -> coalesced triuvec (verbatim R12) ----------------
#define MM8(DST, P, Q) do { if (act) { float s_ = 0.f; \
    _Pragma("unroll") \
    for (int l_ = 0; l_ < 8; ++l_) s_ += P[ii][l_] * Q[l_][jj]; \
    DST[ii][jj] = s_; } __syncthreads(); } while (0)

__global__ __launch_bounds__(256) void k_fin(const float* __restrict__ vfp,
                                             const float* __restrict__ bf,
                                             float* __restrict__ out) {
    int slice = blockIdx.x, b = blockIdx.y;
    int tid = threadIdx.x, d = tid;
    __shared__ float Vl[256][9];
    __shared__ float4 Vl4a[256], Vl4b[256];
    __shared__ float Wr_l[256][8];
    __shared__ float red[256];
    __shared__ float Sp[4][64];
    __shared__ float Sm[8][8], W1[8][8], W2[8][8], YmL[8][8], ZmL[8][8], ZYL[8][8], FmL[8][8];
    float bfv = bf[0];
    float vfl[8];
    #pragma unroll
    for (int g = 0; g < 8; ++g) {
        float acc = 0.f;
        for (int mc = 0; mc < 9; ++mc)
            acc += vfp[(((size_t)b * 8 + g) * 9 + mc) * 256 + d];
        vfl[g] = acc + bfv;
    }
    float mean = 0.f;
    #pragma unroll
    for (int g = 0; g < 8; ++g) mean += vfl[g];
    mean *= 0.125f;
    float trp = 0.f;
    #pragma unroll
    for (int g = 0; g < 8; ++g) { float v = vfl[g] - mean; Vl[d][g] = v; vfl[g] = v; trp += v * v; }
    Vl4a[d] = make_float4(vfl[0], vfl[1], vfl[2], vfl[3]);
    Vl4b[d] = make_float4(vfl[4], vfl[5], vfl[6], vfl[7]);
    red[tid] = trp;
    __syncthreads();
    for (int s = 128; s > 0; s >>= 1) { if (tid < s) red[tid] += red[tid + s]; __syncthreads(); }
    float tr = red[0] * 0.125f;  // trace(cov)
    {
        int q = tid >> 6, l = tid & 63;
        int si = l >> 3, sj = l & 7;
        float sv = 0.f;
        for (int dd = q * 64; dd < q * 64 + 64; ++dd) sv += Vl[dd][si] * Vl[dd][sj];
        Sp[q][l] = sv;
    }
    __syncthreads();
    bool act = tid < 64;
    int ii = (tid >> 3) & 7, jj = tid & 7;
    if (act) Sm[ii][jj] = (Sp[0][tid] + Sp[1][tid] + Sp[2][tid] + Sp[3][tid]) / (8.f * tr);
    __syncthreads();
    if (act) {
        YmL[ii][jj] = (ii == jj ? 1.5f : 0.f) - 0.5f * Sm[ii][jj];
        ZmL[ii][jj] = (ii == jj ? -0.5f : 0.f);
    }
    __syncthreads();
    float ya = 0.f, za = 1.5f;
    MM8(W1, Sm, YmL);
    MM8(W2, ZmL, W1);
    float pa = za * ya;
    if (act) ZYL[ii][jj] = -0.5f * (za * YmL[ii][jj] + ya * ZmL[ii][jj] + W2[ii][jj]);
    __syncthreads();
    float zya = 1.5f - 0.5f * pa;
    MM8(W1, Sm, ZYL);
    MM8(W2, YmL, W1);
    if (act) YmL[ii][jj] = ya * ZYL[ii][jj] + zya * YmL[ii][jj] + W2[ii][jj];
    __syncthreads();
    ya = ya * zya;
    MM8(W1, Sm, ZmL);
    MM8(W2, ZYL, W1);
    if (act) ZmL[ii][jj] = zya * ZmL[ii][jj] + za * ZYL[ii][jj] + W2[ii][jj];
    __syncthreads();
    za = zya * za;
    MM8(W1, Sm, YmL);
    MM8(W2, ZmL, W1);
    float p2a = za * ya;
    if (act) ZYL[ii][jj] = za * YmL[ii][jj] + ya * ZmL[ii][jj] + W2[ii][jj];
    __syncthreads();
    MM8(W1, Sm, ZYL);
    MM8(W2, YmL, W1);
    if (act) FmL[ii][jj] = 0.5f * ((3.f - p2a) * YmL[ii][jj] - ya * ZYL[ii][jj] - W2[ii][jj]);
    __syncthreads();
    float fa = 0.5f * ya * (3.f - p2a);
    float sqtr = sqrtf(tr);
    float scaleF = 1.f / (8.f * sqtr);
    #pragma unroll
    for (int jo = 0; jo < 8; ++jo) {
        float sv = 0.f;
        #pragma unroll
        for (int i = 0; i < 8; ++i) sv += vfl[i] * FmL[i][jo];
        Wr_l[d][jo] = sv * scaleF;
    }
    float s0v = fa * sqtr;
    __syncthreads();
    int dd0 = slice * 32;
    for (int dd = dd0; dd < dd0 + 32; ++dd) {
        int e = tid;
        if (e >= dd) {
            float w0 = Wr_l[dd][0], w1 = Wr_l[dd][1], w2 = Wr_l[dd][2], w3 = Wr_l[dd][3];
            float w4 = Wr_l[dd][4], w5 = Wr_l[dd][5], w6 = Wr_l[dd][6], w7 = Wr_l[dd][7];
            float4 va = Vl4a[e], vb = Vl4b[e];
            float v = w0 * va.x + w1 * va.y + w2 * va.z + w3 * va.w
                    + w4 * vb.x + w5 * vb.y + w6 * vb.z + w7 * vb.w;
            if (e == dd) v += s0v;
            size_t base = (size_t)b * 32896 + (size_t)dd * 256 - ((size_t)dd * (dd - 1)) / 2;
            out[base + (e - dd)] = v;
        }
    }
}

extern "C" void kernel_launch(void* const* d_in, const int* in_sizes, int n_in,
                              void* d_out, int out_size, void* d_ws, size_t ws_size,
                              hipStream_t stream) {
    const float* x    = (const float*)d_in[0];
    const float* cent = (const float*)d_in[1];
    const float* Winp = (const float*)d_in[2];
    const float* binp = (const float*)d_in[3];
    const float* Wg   = (const float*)d_in[4];
    const float* bg   = (const float*)d_in[5];
    const float* Wgk  = (const float*)d_in[6];
    const float* Wf   = (const float*)d_in[8];
    const float* bf   = (const float*)d_in[9];
    float* out = (float*)d_out;
    char* wsb = (char*)d_ws;

    // byte-offset workspace layout
    u16*   xtnb  = (u16*)(wsb);                          // [4096][1024] bf16, 8 MB
    u16*   ltb   = (u16*)(wsb + (8ull << 20));           // em1 [1024][4096] bf16, 8 MB
    u16*   wgkb  = (u16*)(wsb + (16ull << 20));          // [1024][2048] bf16, 4 MB
    u16*   winpT = (u16*)(wsb + (20ull << 20));          // [1024][2048] bf16, 4 MB
    float* wcp   = (float*)(wsb + (24ull << 20));        // [4][1024][1024] f32, 16 MB
    u16*   wcb   = (u16*)(wsb + (40ull << 20));          // [1024][1024] bf16, 2 MB
    float* misc  = (float*)(wsb + (42ull << 20));
    float* wgp   = misc;                 // [8][8][1024] partials (plain stores)
    float* cg    = wgp + 65536;          // [8]
    float* ssum  = cg + 8;               // [1024][4]  (zeroed by k_mid, atomics in logits)
    float* sagm  = ssum + 4096;          // [1024][4]
    float* agT   = sagm + 4096;          // [4][8][1024]
    float* u     = agT + 32768;          // [4][1024]
    float* wfxp  = u + 4096;             // [8][4][8][1024]
    float* vfp   = wfxp + 262144;        // [4][8][9][256]

    k_pre<<<3105, 256, 0, stream>>>(x, Wgk, Winp, Wg, binp, bg, xtnb, wgkb, winpT, wgp, cg);
    // Wc = W_gk @ W_inp: M=1024, N=1024, K=2048 split-K (4 x 512), 64x64 tile -> 1024 blocks (4/CU)
    k_mfma_gemm<0><<<dim3(16, 16, 4), 256, 0, stream>>>(
        wgkb, winpT, wcp, nullptr, nullptr, nullptr, nullptr,
        2048, 512, 1024, 512LL, 512LL, 1048576LL);
    k_mid<<<1153, 256, 0, stream>>>(wcp, wcb, xtnb, wgp, cg, agT, ssum);
    // logits: em1[gk][b*1024+m] = exp(Wc @ xtn^T) - 1 (bf16) + atomic ssum/sagm
    k_mfma_gemm<3><<<dim3(64, 16, 1), 256, 0, stream>>>(
        wcb, xtnb, nullptr, ltb, agT, ssum, sagm,
        1024, 1024, 4096, 0, 0, 0);
    k_wfx2<<<dim3(8, 4, 2), 256, 0, stream>>>(ltb, ssum, sagm, Wf, agT, xtnb, wfxp, u);
    k_vfpart<<<dim3(8, 9), 256, 0, stream>>>(wfxp, winpT, u, cent, binp, vfp);
    k_fin<<<dim3(8, 4), 256, 0, stream>>>(vfp, bf, out);
}

// Round 14
// 172.828 us; speedup vs baseline: 1.1184x; 1.0305x over previous
//
#include <hip/hip_runtime.h>
#include <math.h>

typedef float f32x4 __attribute__((ext_vector_type(4)));
typedef short bf16x8 __attribute__((ext_vector_type(8)));
typedef unsigned short u16;

__device__ __forceinline__ u16 f2bf(float f) {
    unsigned u = __builtin_bit_cast(unsigned, f);
    u += 0x7fff + ((u >> 16) & 1);   // RNE
    return (u16)(u >> 16);
}
__device__ __forceinline__ float bf2f(u16 s) {
    unsigned v = ((unsigned)s) << 16;
    return __builtin_bit_cast(float, v);
}
__device__ __forceinline__ void gload16(const void* g, void* l) {
    __builtin_amdgcn_global_load_lds(
        (const __attribute__((address_space(1))) unsigned int*)g,
        (__attribute__((address_space(3))) unsigned int*)l, 16, 0, 0);
}

// ---------------- K_pre: norm partials (512, COALESCED) | f2bf Wgk (2048) | Winp^T (512)
//                  | wgp partials (32) | cg (1).  LDS overlay 16.7KB -> 8 blocks/CU.
__global__ __launch_bounds__(256) void k_pre(const float* __restrict__ x,
                                             const float* __restrict__ Wgk,
                                             const float* __restrict__ Winp,
                                             const float* __restrict__ Wg,
                                             const float* __restrict__ binp,
                                             const float* __restrict__ bg,
                                             u16* __restrict__ wgkb,
                                             u16* __restrict__ winpT,
                                             float* __restrict__ wgp,
                                             float* __restrict__ cg,
                                             float* __restrict__ normp) {
    __shared__ __align__(16) char smraw[64 * 65 * 4 + 64];   // 16.7 KB overlay
    int bid = blockIdx.x, tid = threadIdx.x;
    if (bid < 512) {
        // phase-1 norms: slab x[b8][cs*64..+64][0..128) read coalesced; per-hw sum of squares
        float (*np)[132] = reinterpret_cast<float(*)[132]>(smraw);  // [8][132]
        int b8 = bid >> 4, cs = bid & 15;
        const float* xs = x + (size_t)b8 * 131072 + (size_t)cs * 8192;
        int hw0 = (tid & 31) * 4, r = tid >> 5;
        float a0 = 0.f, a1 = 0.f, a2 = 0.f, a3 = 0.f;
        #pragma unroll
        for (int i = 0; i < 8; ++i) {
            int c = i * 8 + r;
            float4 v = *(const float4*)(xs + (size_t)c * 128 + hw0);
            a0 += v.x * v.x; a1 += v.y * v.y; a2 += v.z * v.z; a3 += v.w * v.w;
        }
        np[r][hw0 + 0] = a0; np[r][hw0 + 1] = a1;
        np[r][hw0 + 2] = a2; np[r][hw0 + 3] = a3;
        __syncthreads();
        if (tid < 128) {
            float s = 0.f;
            #pragma unroll
            for (int q = 0; q < 8; ++q) s += np[q][tid];
            normp[(size_t)cs * 4096 + b8 * 128 + tid] = s;
        }
    } else if (bid < 2560) {
        int i = ((bid - 512) * 256 + tid) * 4;
        float4 v = *(const float4*)(Wgk + i);
        ushort4 o;
        o.x = f2bf(v.x); o.y = f2bf(v.y); o.z = f2bf(v.z); o.w = f2bf(v.w);
        *(ushort4*)(wgkb + i) = o;
    } else if (bid < 3072) {
        float (*tile)[65] = reinterpret_cast<float(*)[65]>(smraw);   // 16.6 KB
        int tb = bid - 2560;            // 0..511
        int er = tb & 31, cr = tb >> 5; // e-tile(64), c-tile(64)
        #pragma unroll
        for (int i = 0; i < 16; ++i) {
            int idx = tid + i * 256;
            int r = idx >> 6, c = idx & 63;
            tile[r][c] = Winp[(size_t)(er * 64 + r) * 1024 + cr * 64 + c];
        }
        __syncthreads();
        #pragma unroll
        for (int i = 0; i < 16; ++i) {
            int idx = tid + i * 256;
            int cc = idx >> 6, rr = idx & 63;
            winpT[(size_t)(cr * 64 + cc) * 2048 + er * 64 + rr] = f2bf(tile[rr][cc]);
        }
    } else if (bid < 3104) {
        // wgp[eq][g][c] = sum_{e in eq*256..+256} Wg[g][e]*Winp[e][c]   (32 blocks)
        float (*wg_l)[256] = reinterpret_cast<float(*)[256]>(smraw);   // 8 KB
        int t2 = bid - 3072;            // 0..31
        int cq = t2 & 3, eq = t2 >> 2;  // c-chunk(256), e-octant(256)
        #pragma unroll
        for (int i = 0; i < 8; ++i) {
            int idx = tid + i * 256;    // 0..2047
            wg_l[idx >> 8][idx & 255] = Wg[(size_t)(idx >> 8) * 2048 + eq * 256 + (idx & 255)];
        }
        __syncthreads();
        int c = cq * 256 + tid;
        float acc[8] = {};
        #pragma unroll 2
        for (int e = 0; e < 256; ++e) {
            float v = Winp[(size_t)(eq * 256 + e) * 1024 + c];
            #pragma unroll
            for (int g = 0; g < 8; ++g) acc[g] += wg_l[g][e] * v;
        }
        #pragma unroll
        for (int g = 0; g < 8; ++g) wgp[(size_t)eq * 8192 + g * 1024 + c] = acc[g];
    } else {
        // cg[g] = Wg[g,:].b_inp + bg[g]  (8 groups x 32 lanes)
        int g = tid >> 5, sub = tid & 31;
        float t = 0.f;
        for (int e = sub; e < 2048; e += 32) t += Wg[(size_t)g * 2048 + e] * binp[e];
        #pragma unroll
        for (int m = 16; m; m >>= 1) t += __shfl_xor(t, m);
        if (sub == 0) cg[g] = t + bg[g];
    }
}

// ---------------- K2: bf16 MFMA GEMM (BT), 64x64 tile, BK=64, 4 waves (2x2), ring-2,
// counted vmcnt, both-sides chunk-XOR swizzle; 4 blocks/CU.
// MODE 0: f32 out (+split-K z); z>=4 blocks instead run the COALESCED transpose
//   phase-2: x slab -> XOR-swizzled LDS -> scaled bf16 xtn (reuses As/Bs LDS).
// MODE 3: em1=exp(acc)-1 bf16 out + atomic column sums.
template <int MODE>
__global__ __launch_bounds__(256, 4) void k_mfma_gemm(
    const u16* __restrict__ A, const u16* __restrict__ B,
    float* __restrict__ Cf, u16* __restrict__ Cb,
    const float* __restrict__ agT, float* __restrict__ ssum, float* __restrict__ sagm,
    const float* __restrict__ Xsrc, const float* __restrict__ normp,
    u16* __restrict__ xtnOut,
    int Kld, int Kloop, int N,
    long long zA, long long zB, long long zC)
{
    constexpr int MR = 2, NR = 2;
    __shared__ __align__(16) u16 smem[4][4096];   // As = smem[0..1], Bs = smem[2..3]; 32 KB
    __shared__ float inv_s[128];
    int bz = blockIdx.z;
    int tid = threadIdx.x;

    if constexpr (MODE == 0) {
        if (bz >= 4) {
            // transpose phase-2: unit = (bz-4)*256 + by*16 + bx in [0,512)
            float* tile2 = (float*)&smem[0][0];               // [128][64] XOR-swizzled
            int u2 = (bz - 4) * 256 + blockIdx.y * 16 + blockIdx.x;
            int b8 = u2 >> 4, cs = u2 & 15;
            const float* xs = Xsrc + (size_t)b8 * 131072 + (size_t)cs * 8192;
            if (tid < 128) {
                float s = 0.f;
                #pragma unroll
                for (int q = 0; q < 16; ++q) s += normp[(size_t)q * 4096 + b8 * 128 + tid];
                inv_s[tid] = 1.0f / fmaxf(sqrtf(s), 1e-12f);
            }
            int hw0 = (tid & 31) * 4;
            #pragma unroll
            for (int i = 0; i < 8; ++i) {
                int c = i * 8 + (tid >> 5);
                float4 v = *(const float4*)(xs + (size_t)c * 128 + hw0);
                tile2[(hw0 + 0) * 64 + (c ^ ((hw0 + 0) & 31))] = v.x;
                tile2[(hw0 + 1) * 64 + (c ^ ((hw0 + 1) & 31))] = v.y;
                tile2[(hw0 + 2) * 64 + (c ^ ((hw0 + 2) & 31))] = v.z;
                tile2[(hw0 + 3) * 64 + (c ^ ((hw0 + 3) & 31))] = v.w;
            }
            __syncthreads();
            #pragma unroll
            for (int it = 0; it < 8; ++it) {
                int hw = it * 16 + (tid >> 4), cl4 = (tid & 15) * 4;
                float iv = inv_s[hw];
                ushort4 o;
                o.x = f2bf(tile2[hw * 64 + ((cl4 + 0) ^ (hw & 31))] * iv);
                o.y = f2bf(tile2[hw * 64 + ((cl4 + 1) ^ (hw & 31))] * iv);
                o.z = f2bf(tile2[hw * 64 + ((cl4 + 2) ^ (hw & 31))] * iv);
                o.w = f2bf(tile2[hw * 64 + ((cl4 + 3) ^ (hw & 31))] * iv);
                *(ushort4*)(xtnOut + (size_t)(b8 * 128 + hw) * 1024 + cs * 64 + cl4) = o;
            }
            return;
        }
    }

    u16 (*As)[4096] = &smem[0];
    u16 (*Bs)[4096] = &smem[2];
    A += (size_t)bz * zA; B += (size_t)bz * zB;
    int lane = tid & 63, wave = tid >> 6;
    int wr = wave >> 1, wc = wave & 1;
    int i0 = blockIdx.y * 64, j0 = blockIdx.x * 64;
    int fr = lane & 15, fg = lane >> 4;
    f32x4 acc[MR][NR] = {};

    int srcOff = ((tid & 7) ^ ((tid >> 3) & 7)) * 8;
    int srow = tid >> 3;

    auto stage = [&](int buf, int t) {
        int kt = t * 64;
        #pragma unroll
        for (int q = 0; q < 2; ++q)
            gload16(A + (size_t)(i0 + q * 32 + srow) * Kld + kt + srcOff,
                    &As[buf][(q * 256 + wave * 64) * 8]);
        #pragma unroll
        for (int q = 0; q < 2; ++q)
            gload16(B + (size_t)(j0 + q * 32 + srow) * Kld + kt + srcOff,
                    &Bs[buf][(q * 256 + wave * 64) * 8]);
    };
    auto compute = [&](int buf) {
        #pragma unroll
        for (int h = 0; h < 2; ++h) {
            bf16x8 af[MR], bv[NR];
            #pragma unroll
            for (int mi = 0; mi < MR; ++mi) {
                int row = wr * 32 + mi * 16 + fr;
                af[mi] = *(const bf16x8*)&As[buf][row * 64 + (((h * 4 + fg) ^ (fr & 7)) * 8)];
            }
            #pragma unroll
            for (int ni = 0; ni < NR; ++ni) {
                int row = wc * 32 + ni * 16 + fr;
                bv[ni] = *(const bf16x8*)&Bs[buf][row * 64 + (((h * 4 + fg) ^ (fr & 7)) * 8)];
            }
            #pragma unroll
            for (int mi = 0; mi < MR; ++mi)
                #pragma unroll
                for (int ni = 0; ni < NR; ++ni)
                    acc[mi][ni] = __builtin_amdgcn_mfma_f32_16x16x32_bf16(
                        af[mi], bv[ni], acc[mi][ni], 0, 0, 0);
        }
    };

    int nk = Kloop >> 6;
    stage(0, 0);
    int cur = 0;
    for (int t = 0; t < nk; ++t) {
        if (t + 1 < nk) {
            stage(cur ^ 1, t + 1);
            asm volatile("s_waitcnt vmcnt(4)" ::: "memory");
        } else {
            asm volatile("s_waitcnt vmcnt(0)" ::: "memory");
        }
        __builtin_amdgcn_s_barrier();
        __builtin_amdgcn_sched_barrier(0);
        compute(cur);
        __builtin_amdgcn_s_barrier();
        cur ^= 1;
    }

    if constexpr (MODE == 3) {
        int bcol = j0 >> 10;
        int g = i0 >> 7;
        float ag2[NR];
        #pragma unroll
        for (int ni = 0; ni < NR; ++ni) {
            int col = j0 + wc * 32 + ni * 16 + fr;
            ag2[ni] = agT[((size_t)bcol * 8 + g) * 1024 + (col & 1023)];
        }
        #pragma unroll
        for (int mi = 0; mi < MR; ++mi)
            #pragma unroll
            for (int r = 0; r < 4; ++r) {
                int row = i0 + wr * 32 + mi * 16 + fg * 4 + r;
                float es = 0.f, sa = 0.f;
                #pragma unroll
                for (int ni = 0; ni < NR; ++ni) {
                    int col = j0 + wc * 32 + ni * 16 + fr;
                    float e = expf(acc[mi][ni][r]);
                    es += e; sa += ag2[ni] * e;
                    Cb[(size_t)row * N + col] = f2bf(e - 1.f);
                }
                #pragma unroll
                for (int m = 8; m; m >>= 1) { es += __shfl_xor(es, m); sa += __shfl_xor(sa, m); }
                if (fr == 0) {
                    atomicAdd(&ssum[row * 4 + bcol], es);
                    atomicAdd(&sagm[row * 4 + bcol], sa);
                }
            }
    } else {
        float* C2 = Cf + (size_t)bz * zC;
        #pragma unroll
        for (int ni = 0; ni < NR; ++ni) {
            int col = j0 + wc * 32 + ni * 16 + fr;
            #pragma unroll
            for (int mi = 0; mi < MR; ++mi)
                #pragma unroll
                for (int r = 0; r < 4; ++r) {
                    int row = i0 + wr * 32 + mi * 16 + fg * 4 + r;
                    C2[(size_t)row * N + col] = acc[mi][ni][r];
                }
        }
    }
}

// ---------------- K_mid: wcred (1024) | agT from 8 wgp partials (128) | zero ssum/sagm (1) ----------------
__global__ __launch_bounds__(256) void k_mid(const float* __restrict__ wcp,
                                             u16* __restrict__ wcb,
                                             const u16* __restrict__ xtn,
                                             const float* __restrict__ wgp,
                                             const float* __restrict__ cg,
                                             float* __restrict__ agT,
                                             float* __restrict__ zz) {
    int bid = blockIdx.x, tid = threadIdx.x;
    if (bid < 1024) {
        int i = (bid * 256 + tid) * 4;
        float4 a = *(const float4*)(wcp + i);
        float4 b = *(const float4*)(wcp + 1048576 + i);
        float4 c = *(const float4*)(wcp + 2097152 + i);
        float4 d = *(const float4*)(wcp + 3145728 + i);
        ushort4 o;
        o.x = f2bf(a.x + b.x + c.x + d.x);
        o.y = f2bf(a.y + b.y + c.y + d.y);
        o.z = f2bf(a.z + b.z + c.z + d.z);
        o.w = f2bf(a.w + b.w + c.w + d.w);
        *(ushort4*)(wcb + i) = o;
    } else if (bid < 1152) {
        // agT[b][g][m] = sigmoid(Wg_eff . xtn[b,m,:] + c_g), Wg_eff = sum of 8 wgp partials
        int t2 = bid - 1024;
        int b = t2 >> 5, ms = t2 & 31;
        int w = tid >> 6, lane = tid & 63;
        __shared__ float wgel[8192];
        __shared__ float cgl[8];
        #pragma unroll
        for (int i = 0; i < 8; ++i) {
            int idx = (tid + i * 256) * 4;
            float4 s = *(const float4*)&wgp[idx];
            #pragma unroll
            for (int eq = 1; eq < 8; ++eq) {
                float4 p = *(const float4*)&wgp[(size_t)eq * 8192 + idx];
                s.x += p.x; s.y += p.y; s.z += p.z; s.w += p.w;
            }
            *(float4*)&wgel[idx] = s;
        }
        if (tid < 8) cgl[tid] = cg[tid];
        __syncthreads();
        for (int r = 0; r < 8; ++r) {
            int m = ms * 32 + w * 8 + r;
            const u16* xr = xtn + ((size_t)b * 1024 + m) * 1024;
            float acc[8] = {};
            #pragma unroll
            for (int i = 0; i < 2; ++i) {
                int c0 = i * 512 + lane * 8;
                bf16x8 hv = *(const bf16x8*)(xr + c0);
                float xf[8];
                #pragma unroll
                for (int j = 0; j < 8; ++j) xf[j] = bf2f((u16)hv[j]);
                #pragma unroll
                for (int g = 0; g < 8; ++g) {
                    float4 wa = *(const float4*)&wgel[g * 1024 + c0];
                    float4 wb = *(const float4*)&wgel[g * 1024 + c0 + 4];
                    acc[g] += xf[0] * wa.x + xf[1] * wa.y + xf[2] * wa.z + xf[3] * wa.w
                            + xf[4] * wb.x + xf[5] * wb.y + xf[6] * wb.z + xf[7] * wb.w;
                }
            }
            #pragma unroll
            for (int g = 0; g < 8; ++g)
                #pragma unroll
                for (int off = 32; off; off >>= 1) acc[g] += __shfl_xor(acc[g], off);
            if (lane < 8)
                agT[((size_t)b * 8 + lane) * 1024 + m] =
                    1.f / (1.f + expf(-(acc[lane] + cgl[lane])));
        }
    } else {
        float4 z = make_float4(0.f, 0.f, 0.f, 0.f);
        #pragma unroll
        for (int i = 0; i < 8; ++i)
            *(float4*)&zz[(tid + i * 256) * 4] = z;
    }
}

// ---------------- K_wfx2: fused wf + wfx.  grid (ms 8, b 4, gh 2)  (verbatim, passed) ----------------
__global__ __launch_bounds__(256) void k_wfx2(const u16* __restrict__ em1,
                                              const float* __restrict__ ssum,
                                              const float* __restrict__ sagm,
                                              const float* __restrict__ Wf,
                                              const float* __restrict__ agT,
                                              const u16* __restrict__ xtn,
                                              float* __restrict__ wfxp,
                                              float* __restrict__ u) {
    int ms = blockIdx.x, b = blockIdx.y, gh = blockIdx.z;
    int tid = threadIdx.x;
    int g0 = gh * 4;
    __shared__ float c1[512];
    __shared__ float C0[4];
    __shared__ float wf_l[4][128];
    #pragma unroll
    for (int i = 0; i < 2; ++i) {
        int kk = tid + i * 256;              // 0..511
        int gk = g0 * 128 + kk;
        float cv = Wf[gk & 127] / ssum[gk * 4 + b];
        c1[kk] = cv;
        if (ms == 0) u[(size_t)b * 1024 + gk] = cv * sagm[gk * 4 + b];
    }
    __syncthreads();
    {
        int w = tid >> 6, l = tid & 63;
        float s = c1[w * 128 + l] + c1[w * 128 + 64 + l];
        #pragma unroll
        for (int m = 32; m; m >>= 1) s += __shfl_xor(s, m);
        if (l == 0) C0[w] = s;
    }
    __syncthreads();
    {
        int w = tid >> 6, l = tid & 63;
        int g = g0 + w;
        float a0 = 0.f, a1 = 0.f;
        const u16* base = em1 + (size_t)(g * 128) * 4096 + b * 1024 + ms * 128 + 2 * l;
        for (int k = 0; k < 128; ++k) {
            unsigned pr = *(const unsigned*)(base + (size_t)k * 4096);
            float cv = c1[w * 128 + k];
            a0 += cv * bf2f((u16)(pr & 0xffff));
            a1 += cv * bf2f((u16)(pr >> 16));
        }
        float c0v = C0[w];
        const float* agp = agT + ((size_t)b * 8 + g) * 1024 + ms * 128;
        wf_l[w][2 * l]     = (c0v + a0) * agp[2 * l];
        wf_l[w][2 * l + 1] = (c0v + a1) * agp[2 * l + 1];
    }
    __syncthreads();
    #pragma unroll
    for (int cs = 0; cs < 4; ++cs) {
        int c = cs * 256 + tid;
        float acc[4] = {};
        const u16* xb = xtn + ((size_t)b * 1024 + ms * 128) * 1024 + c;
        for (int m = 0; m < 128; ++m) {
            float xv = bf2f(xb[(size_t)m * 1024]);
            #pragma unroll
            for (int lg = 0; lg < 4; ++lg) acc[lg] += wf_l[lg][m] * xv;
        }
        #pragma unroll
        for (int lg = 0; lg < 4; ++lg)
            wfxp[(((size_t)ms * 4 + b) * 8 + g0 + lg) * 1024 + c] = acc[lg];
    }
}

// ---------------- K_vfpart (verbatim, passed) ----------------
__global__ __launch_bounds__(256) void k_vfpart(const float* __restrict__ wfxp,
                                                const u16* __restrict__ winpT,
                                                const float* __restrict__ u,
                                                const float* __restrict__ cent,
                                                const float* __restrict__ binp,
                                                float* __restrict__ vfp) {
    int g = blockIdx.x, cs = blockIdx.y;  // (8, 9)
    int tid = threadIdx.x;
    if (cs < 8) {
        __shared__ float wfx_l[4][128];
        #pragma unroll
        for (int i = 0; i < 2; ++i) {
            int idx = tid + i * 256;
            int bb = idx >> 7, c2 = idx & 127;
            float s = 0.f;
            #pragma unroll
            for (int msq = 0; msq < 8; ++msq)
                s += wfxp[(((size_t)msq * 4 + bb) * 8 + g) * 1024 + cs * 128 + c2];
            wfx_l[bb][c2] = s;
        }
        __syncthreads();
        int d = tid;
        float acc[4] = {};
        for (int c2 = 0; c2 < 128; ++c2) {
            float wv = bf2f(winpT[(size_t)(cs * 128 + c2) * 2048 + g * 256 + d]);
            #pragma unroll
            for (int bb = 0; bb < 4; ++bb) acc[bb] += wfx_l[bb][c2] * wv;
        }
        #pragma unroll
        for (int bb = 0; bb < 4; ++bb)
            vfp[(((size_t)bb * 8 + g) * 9 + cs) * 256 + d] = acc[bb];
    } else {
        __shared__ float ul[4][128];
        __shared__ float swl[4];
        #pragma unroll
        for (int i = 0; i < 2; ++i) {
            int idx = tid + i * 256;
            ul[idx >> 7][idx & 127] = u[((size_t)(idx >> 7) * 8 + g) * 128 + (idx & 127)];
        }
        __syncthreads();
        if (tid < 4) {
            float s = 0.f;
            for (int k = 0; k < 128; ++k) s += ul[tid][k];
            swl[tid] = s;
        }
        __syncthreads();
        int d = tid;
        float acc[4] = {};
        for (int k = 0; k < 128; ++k) {
            float cv = cent[k * 256 + d];
            #pragma unroll
            for (int bb = 0; bb < 4; ++bb) acc[bb] -= ul[bb][k] * cv;
        }
        float bi = binp[g * 256 + d];
        #pragma unroll
        for (int bb = 0; bb < 4; ++bb)
            vfp[(((size_t)bb * 8 + g) * 9 + 8) * 256 + d] = acc[bb] + swl[bb] * bi;
    }
}

// ---------------- K_fin: finalize vf -> rank-8 NS -> coalesced triuvec (verbatim) ----------------
#define MM8(DST, P, Q) do { if (act) { float s_ = 0.f; \
    _Pragma("unroll") \
    for (int l_ = 0; l_ < 8; ++l_) s_ += P[ii][l_] * Q[l_][jj]; \
    DST[ii][jj] = s_; } __syncthreads(); } while (0)

__global__ __launch_bounds__(256) void k_fin(const float* __restrict__ vfp,
                                             const float* __restrict__ bf,
                                             float* __restrict__ out) {
    int slice = blockIdx.x, b = blockIdx.y;
    int tid = threadIdx.x, d = tid;
    __shared__ float Vl[256][9];
    __shared__ float4 Vl4a[256], Vl4b[256];
    __shared__ float Wr_l[256][8];
    __shared__ float red[256];
    __shared__ float Sp[4][64];
    __shared__ float Sm[8][8], W1[8][8], W2[8][8], YmL[8][8], ZmL[8][8], ZYL[8][8], FmL[8][8];
    float bfv = bf[0];
    float vfl[8];
    #pragma unroll
    for (int g = 0; g < 8; ++g) {
        float acc = 0.f;
        for (int mc = 0; mc < 9; ++mc)
            acc += vfp[(((size_t)b * 8 + g) * 9 + mc) * 256 + d];
        vfl[g] = acc + bfv;
    }
    float mean = 0.f;
    #pragma unroll
    for (int g = 0; g < 8; ++g) mean += vfl[g];
    mean *= 0.125f;
    float trp = 0.f;
    #pragma unroll
    for (int g = 0; g < 8; ++g) { float v = vfl[g] - mean; Vl[d][g] = v; vfl[g] = v; trp += v * v; }
    Vl4a[d] = make_float4(vfl[0], vfl[1], vfl[2], vfl[3]);
    Vl4b[d] = make_float4(vfl[4], vfl[5], vfl[6], vfl[7]);
    red[tid] = trp;
    __syncthreads();
    for (int s = 128; s > 0; s >>= 1) { if (tid < s) red[tid] += red[tid + s]; __syncthreads(); }
    float tr = red[0] * 0.125f;  // trace(cov)
    {
        int q = tid >> 6, l = tid & 63;
        int si = l >> 3, sj = l & 7;
        float sv = 0.f;
        for (int dd = q * 64; dd < q * 64 + 64; ++dd) sv += Vl[dd][si] * Vl[dd][sj];
        Sp[q][l] = sv;
    }
    __syncthreads();
    bool act = tid < 64;
    int ii = (tid >> 3) & 7, jj = tid & 7;
    if (act) Sm[ii][jj] = (Sp[0][tid] + Sp[1][tid] + Sp[2][tid] + Sp[3][tid]) / (8.f * tr);
    __syncthreads();
    if (act) {
        YmL[ii][jj] = (ii == jj ? 1.5f : 0.f) - 0.5f * Sm[ii][jj];
        ZmL[ii][jj] = (ii == jj ? -0.5f : 0.f);
    }
    __syncthreads();
    float ya = 0.f, za = 1.5f;
    MM8(W1, Sm, YmL);
    MM8(W2, ZmL, W1);
    float pa = za * ya;
    if (act) ZYL[ii][jj] = -0.5f * (za * YmL[ii][jj] + ya * ZmL[ii][jj] + W2[ii][jj]);
    __syncthreads();
    float zya = 1.5f - 0.5f * pa;
    MM8(W1, Sm, ZYL);
    MM8(W2, YmL, W1);
    if (act) YmL[ii][jj] = ya * ZYL[ii][jj] + zya * YmL[ii][jj] + W2[ii][jj];
    __syncthreads();
    ya = ya * zya;
    MM8(W1, Sm, ZmL);
    MM8(W2, ZYL, W1);
    if (act) ZmL[ii][jj] = zya * ZmL[ii][jj] + za * ZYL[ii][jj] + W2[ii][jj];
    __syncthreads();
    za = zya * za;
    MM8(W1, Sm, YmL);
    MM8(W2, ZmL, W1);
    float p2a = za * ya;
    if (act) ZYL[ii][jj] = za * YmL[ii][jj] + ya * ZmL[ii][jj] + W2[ii][jj];
    __syncthreads();
    MM8(W1, Sm, ZYL);
    MM8(W2, YmL, W1);
    if (act) FmL[ii][jj] = 0.5f * ((3.f - p2a) * YmL[ii][jj] - ya * ZYL[ii][jj] - W2[ii][jj]);
    __syncthreads();
    float fa = 0.5f * ya * (3.f - p2a);
    float sqtr = sqrtf(tr);
    float scaleF = 1.f / (8.f * sqtr);
    #pragma unroll
    for (int jo = 0; jo < 8; ++jo) {
        float sv = 0.f;
        #pragma unroll
        for (int i = 0; i < 8; ++i) sv += vfl[i] * FmL[i][jo];
        Wr_l[d][jo] = sv * scaleF;
    }
    float s0v = fa * sqtr;
    __syncthreads();
    int dd0 = slice * 32;
    for (int dd = dd0; dd < dd0 + 32; ++dd) {
        int e = tid;
        if (e >= dd) {
            float w0 = Wr_l[dd][0], w1 = Wr_l[dd][1], w2 = Wr_l[dd][2], w3 = Wr_l[dd][3];
            float w4 = Wr_l[dd][4], w5 = Wr_l[dd][5], w6 = Wr_l[dd][6], w7 = Wr_l[dd][7];
            float4 va = Vl4a[e], vb = Vl4b[e];
            float v = w0 * va.x + w1 * va.y + w2 * va.z + w3 * va.w
                    + w4 * vb.x + w5 * vb.y + w6 * vb.z + w7 * vb.w;
            if (e == dd) v += s0v;
            size_t base = (size_t)b * 32896 + (size_t)dd * 256 - ((size_t)dd * (dd - 1)) / 2;
            out[base + (e - dd)] = v;
        }
    }
}

extern "C" void kernel_launch(void* const* d_in, const int* in_sizes, int n_in,
                              void* d_out, int out_size, void* d_ws, size_t ws_size,
                              hipStream_t stream) {
    const float* x    = (const float*)d_in[0];
    const float* cent = (const float*)d_in[1];
    const float* Winp = (const float*)d_in[2];
    const float* binp = (const float*)d_in[3];
    const float* Wg   = (const float*)d_in[4];
    const float* bg   = (const float*)d_in[5];
    const float* Wgk  = (const float*)d_in[6];
    const float* Wf   = (const float*)d_in[8];
    const float* bf   = (const float*)d_in[9];
    float* out = (float*)d_out;
    char* wsb = (char*)d_ws;

    // byte-offset workspace layout
    u16*   xtnb  = (u16*)(wsb);                          // [4096][1024] bf16, 8 MB
    u16*   ltb   = (u16*)(wsb + (8ull << 20));           // em1 [1024][4096] bf16, 8 MB
    u16*   wgkb  = (u16*)(wsb + (16ull << 20));          // [1024][2048] bf16, 4 MB
    u16*   winpT = (u16*)(wsb + (20ull << 20));          // [1024][2048] bf16, 4 MB
    float* wcp   = (float*)(wsb + (24ull << 20));        // [4][1024][1024] f32, 16 MB
    u16*   wcb   = (u16*)(wsb + (40ull << 20));          // [1024][1024] bf16, 2 MB
    float* misc  = (float*)(wsb + (42ull << 20));
    float* wgp   = misc;                 // [8][8][1024] partials
    float* cg    = wgp + 65536;          // [8]
    float* ssum  = cg + 8;               // [1024][4]  (zeroed by k_mid)
    float* sagm  = ssum + 4096;          // [1024][4]
    float* agT   = sagm + 4096;          // [4][8][1024]
    float* u     = agT + 32768;          // [4][1024]
    float* wfxp  = u + 4096;             // [8][4][8][1024]
    float* vfp   = wfxp + 262144;        // [4][8][9][256]
    float* normp = vfp + 73728;          // [16][4096] norm partials

    k_pre<<<3105, 256, 0, stream>>>(x, Wgk, Winp, Wg, binp, bg, wgkb, winpT, wgp, cg, normp);
    // Wc GEMM (z 0..3) + transpose phase-2 (z 4..5): 1536 blocks
    k_mfma_gemm<0><<<dim3(16, 16, 6), 256, 0, stream>>>(
        wgkb, winpT, wcp, nullptr, nullptr, nullptr, nullptr,
        x, normp, xtnb,
        2048, 512, 1024, 512LL, 512LL, 1048576LL);
    k_mid<<<1153, 256, 0, stream>>>(wcp, wcb, xtnb, wgp, cg, agT, ssum);
    // logits: em1[gk][b*1024+m] = exp(Wc @ xtn^T) - 1 (bf16) + atomic ssum/sagm
    k_mfma_gemm<3><<<dim3(64, 16, 1), 256, 0, stream>>>(
        wcb, xtnb, nullptr, ltb, agT, ssum, sagm,
        nullptr, nullptr, nullptr,
        1024, 1024, 4096, 0, 0, 0);
    k_wfx2<<<dim3(8, 4, 2), 256, 0, stream>>>(ltb, ssum, sagm, Wf, agT, xtnb, wfxp, u);
    k_vfpart<<<dim3(8, 9), 256, 0, stream>>>(wfxp, winpT, u, cent, binp, vfp);
    k_fin<<<dim3(8, 4), 256, 0, stream>>>(vfp, bf, out);
}

// Round 15
// 154.131 us; speedup vs baseline: 1.2541x; 1.1213x over previous
//
#include <hip/hip_runtime.h>
#include <math.h>

typedef float f32x4 __attribute__((ext_vector_type(4)));
typedef short bf16x8 __attribute__((ext_vector_type(8)));
typedef unsigned short u16;

__device__ __forceinline__ u16 f2bf(float f) {
    unsigned u = __builtin_bit_cast(unsigned, f);
    u += 0x7fff + ((u >> 16) & 1);   // RNE
    return (u16)(u >> 16);
}
__device__ __forceinline__ float bf2f(u16 s) {
    unsigned v = ((unsigned)s) << 16;
    return __builtin_bit_cast(float, v);
}
__device__ __forceinline__ void gload16(const void* g, void* l) {
    __builtin_amdgcn_global_load_lds(
        (const __attribute__((address_space(1))) unsigned int*)g,
        (__attribute__((address_space(3))) unsigned int*)l, 16, 0, 0);
}

// ---------------- K_pre: norm partials (512, COALESCED) | f2bf Wgk (2048) | Winp^T (512)
//                  | wgp partials (32) | cg (1).  LDS overlay 16.7KB.  (verbatim R14, passed)
__global__ __launch_bounds__(256) void k_pre(const float* __restrict__ x,
                                             const float* __restrict__ Wgk,
                                             const float* __restrict__ Winp,
                                             const float* __restrict__ Wg,
                                             const float* __restrict__ binp,
                                             const float* __restrict__ bg,
                                             u16* __restrict__ wgkb,
                                             u16* __restrict__ winpT,
                                             float* __restrict__ wgp,
                                             float* __restrict__ cg,
                                             float* __restrict__ normp) {
    __shared__ __align__(16) char smraw[64 * 65 * 4 + 64];   // 16.7 KB overlay
    int bid = blockIdx.x, tid = threadIdx.x;
    if (bid < 512) {
        float (*np)[132] = reinterpret_cast<float(*)[132]>(smraw);  // [8][132]
        int b8 = bid >> 4, cs = bid & 15;
        const float* xs = x + (size_t)b8 * 131072 + (size_t)cs * 8192;
        int hw0 = (tid & 31) * 4, r = tid >> 5;
        float a0 = 0.f, a1 = 0.f, a2 = 0.f, a3 = 0.f;
        #pragma unroll
        for (int i = 0; i < 8; ++i) {
            int c = i * 8 + r;
            float4 v = *(const float4*)(xs + (size_t)c * 128 + hw0);
            a0 += v.x * v.x; a1 += v.y * v.y; a2 += v.z * v.z; a3 += v.w * v.w;
        }
        np[r][hw0 + 0] = a0; np[r][hw0 + 1] = a1;
        np[r][hw0 + 2] = a2; np[r][hw0 + 3] = a3;
        __syncthreads();
        if (tid < 128) {
            float s = 0.f;
            #pragma unroll
            for (int q = 0; q < 8; ++q) s += np[q][tid];
            normp[(size_t)cs * 4096 + b8 * 128 + tid] = s;
        }
    } else if (bid < 2560) {
        int i = ((bid - 512) * 256 + tid) * 4;
        float4 v = *(const float4*)(Wgk + i);
        ushort4 o;
        o.x = f2bf(v.x); o.y = f2bf(v.y); o.z = f2bf(v.z); o.w = f2bf(v.w);
        *(ushort4*)(wgkb + i) = o;
    } else if (bid < 3072) {
        float (*tile)[65] = reinterpret_cast<float(*)[65]>(smraw);   // 16.6 KB
        int tb = bid - 2560;            // 0..511
        int er = tb & 31, cr = tb >> 5; // e-tile(64), c-tile(64)
        #pragma unroll
        for (int i = 0; i < 16; ++i) {
            int idx = tid + i * 256;
            int r = idx >> 6, c = idx & 63;
            tile[r][c] = Winp[(size_t)(er * 64 + r) * 1024 + cr * 64 + c];
        }
        __syncthreads();
        #pragma unroll
        for (int i = 0; i < 16; ++i) {
            int idx = tid + i * 256;
            int cc = idx >> 6, rr = idx & 63;
            winpT[(size_t)(cr * 64 + cc) * 2048 + er * 64 + rr] = f2bf(tile[rr][cc]);
        }
    } else if (bid < 3104) {
        float (*wg_l)[256] = reinterpret_cast<float(*)[256]>(smraw);   // 8 KB
        int t2 = bid - 3072;            // 0..31
        int cq = t2 & 3, eq = t2 >> 2;  // c-chunk(256), e-octant(256)
        #pragma unroll
        for (int i = 0; i < 8; ++i) {
            int idx = tid + i * 256;    // 0..2047
            wg_l[idx >> 8][idx & 255] = Wg[(size_t)(idx >> 8) * 2048 + eq * 256 + (idx & 255)];
        }
        __syncthreads();
        int c = cq * 256 + tid;
        float acc[8] = {};
        #pragma unroll 2
        for (int e = 0; e < 256; ++e) {
            float v = Winp[(size_t)(eq * 256 + e) * 1024 + c];
            #pragma unroll
            for (int g = 0; g < 8; ++g) acc[g] += wg_l[g][e] * v;
        }
        #pragma unroll
        for (int g = 0; g < 8; ++g) wgp[(size_t)eq * 8192 + g * 1024 + c] = acc[g];
    } else {
        int g = tid >> 5, sub = tid & 31;
        float t = 0.f;
        for (int e = sub; e < 2048; e += 32) t += Wg[(size_t)g * 2048 + e] * binp[e];
        #pragma unroll
        for (int m = 16; m; m >>= 1) t += __shfl_xor(t, m);
        if (sub == 0) cg[g] = t + bg[g];
    }
}

// ---------------- K2: bf16 MFMA GEMM (BT), 64x64 tile, BK=64, 4 waves, ring-2,
// counted vmcnt, both-sides chunk-XOR swizzle; 4 blocks/CU.  (verbatim R14, passed)
// MODE 0: f32 out (+split-K z); z>=4 blocks run the coalesced transpose phase-2.
// MODE 3: em1=exp(acc)-1 bf16 out + atomic column sums.
template <int MODE>
__global__ __launch_bounds__(256, 4) void k_mfma_gemm(
    const u16* __restrict__ A, const u16* __restrict__ B,
    float* __restrict__ Cf, u16* __restrict__ Cb,
    const float* __restrict__ agT, float* __restrict__ ssum, float* __restrict__ sagm,
    const float* __restrict__ Xsrc, const float* __restrict__ normp,
    u16* __restrict__ xtnOut,
    int Kld, int Kloop, int N,
    long long zA, long long zB, long long zC)
{
    constexpr int MR = 2, NR = 2;
    __shared__ __align__(16) u16 smem[4][4096];   // 32 KB
    __shared__ float inv_s[128];
    int bz = blockIdx.z;
    int tid = threadIdx.x;

    if constexpr (MODE == 0) {
        if (bz >= 4) {
            float* tile2 = (float*)&smem[0][0];               // [128][64] XOR-swizzled
            int u2 = (bz - 4) * 256 + blockIdx.y * 16 + blockIdx.x;
            int b8 = u2 >> 4, cs = u2 & 15;
            const float* xs = Xsrc + (size_t)b8 * 131072 + (size_t)cs * 8192;
            if (tid < 128) {
                float s = 0.f;
                #pragma unroll
                for (int q = 0; q < 16; ++q) s += normp[(size_t)q * 4096 + b8 * 128 + tid];
                inv_s[tid] = 1.0f / fmaxf(sqrtf(s), 1e-12f);
            }
            int hw0 = (tid & 31) * 4;
            #pragma unroll
            for (int i = 0; i < 8; ++i) {
                int c = i * 8 + (tid >> 5);
                float4 v = *(const float4*)(xs + (size_t)c * 128 + hw0);
                tile2[(hw0 + 0) * 64 + (c ^ ((hw0 + 0) & 31))] = v.x;
                tile2[(hw0 + 1) * 64 + (c ^ ((hw0 + 1) & 31))] = v.y;
                tile2[(hw0 + 2) * 64 + (c ^ ((hw0 + 2) & 31))] = v.z;
                tile2[(hw0 + 3) * 64 + (c ^ ((hw0 + 3) & 31))] = v.w;
            }
            __syncthreads();
            #pragma unroll
            for (int it = 0; it < 8; ++it) {
                int hw = it * 16 + (tid >> 4), cl4 = (tid & 15) * 4;
                float iv = inv_s[hw];
                ushort4 o;
                o.x = f2bf(tile2[hw * 64 + ((cl4 + 0) ^ (hw & 31))] * iv);
                o.y = f2bf(tile2[hw * 64 + ((cl4 + 1) ^ (hw & 31))] * iv);
                o.z = f2bf(tile2[hw * 64 + ((cl4 + 2) ^ (hw & 31))] * iv);
                o.w = f2bf(tile2[hw * 64 + ((cl4 + 3) ^ (hw & 31))] * iv);
                *(ushort4*)(xtnOut + (size_t)(b8 * 128 + hw) * 1024 + cs * 64 + cl4) = o;
            }
            return;
        }
    }

    u16 (*As)[4096] = &smem[0];
    u16 (*Bs)[4096] = &smem[2];
    A += (size_t)bz * zA; B += (size_t)bz * zB;
    int lane = tid & 63, wave = tid >> 6;
    int wr = wave >> 1, wc = wave & 1;
    int i0 = blockIdx.y * 64, j0 = blockIdx.x * 64;
    int fr = lane & 15, fg = lane >> 4;
    f32x4 acc[MR][NR] = {};

    int srcOff = ((tid & 7) ^ ((tid >> 3) & 7)) * 8;
    int srow = tid >> 3;

    auto stage = [&](int buf, int t) {
        int kt = t * 64;
        #pragma unroll
        for (int q = 0; q < 2; ++q)
            gload16(A + (size_t)(i0 + q * 32 + srow) * Kld + kt + srcOff,
                    &As[buf][(q * 256 + wave * 64) * 8]);
        #pragma unroll
        for (int q = 0; q < 2; ++q)
            gload16(B + (size_t)(j0 + q * 32 + srow) * Kld + kt + srcOff,
                    &Bs[buf][(q * 256 + wave * 64) * 8]);
    };
    auto compute = [&](int buf) {
        #pragma unroll
        for (int h = 0; h < 2; ++h) {
            bf16x8 af[MR], bv[NR];
            #pragma unroll
            for (int mi = 0; mi < MR; ++mi) {
                int row = wr * 32 + mi * 16 + fr;
                af[mi] = *(const bf16x8*)&As[buf][row * 64 + (((h * 4 + fg) ^ (fr & 7)) * 8)];
            }
            #pragma unroll
            for (int ni = 0; ni < NR; ++ni) {
                int row = wc * 32 + ni * 16 + fr;
                bv[ni] = *(const bf16x8*)&Bs[buf][row * 64 + (((h * 4 + fg) ^ (fr & 7)) * 8)];
            }
            #pragma unroll
            for (int mi = 0; mi < MR; ++mi)
                #pragma unroll
                for (int ni = 0; ni < NR; ++ni)
                    acc[mi][ni] = __builtin_amdgcn_mfma_f32_16x16x32_bf16(
                        af[mi], bv[ni], acc[mi][ni], 0, 0, 0);
        }
    };

    int nk = Kloop >> 6;
    stage(0, 0);
    int cur = 0;
    for (int t = 0; t < nk; ++t) {
        if (t + 1 < nk) {
            stage(cur ^ 1, t + 1);
            asm volatile("s_waitcnt vmcnt(4)" ::: "memory");
        } else {
            asm volatile("s_waitcnt vmcnt(0)" ::: "memory");
        }
        __builtin_amdgcn_s_barrier();
        __builtin_amdgcn_sched_barrier(0);
        compute(cur);
        __builtin_amdgcn_s_barrier();
        cur ^= 1;
    }

    if constexpr (MODE == 3) {
        int bcol = j0 >> 10;
        int g = i0 >> 7;
        float ag2[NR];
        #pragma unroll
        for (int ni = 0; ni < NR; ++ni) {
            int col = j0 + wc * 32 + ni * 16 + fr;
            ag2[ni] = agT[((size_t)bcol * 8 + g) * 1024 + (col & 1023)];
        }
        #pragma unroll
        for (int mi = 0; mi < MR; ++mi)
            #pragma unroll
            for (int r = 0; r < 4; ++r) {
                int row = i0 + wr * 32 + mi * 16 + fg * 4 + r;
                float es = 0.f, sa = 0.f;
                #pragma unroll
                for (int ni = 0; ni < NR; ++ni) {
                    int col = j0 + wc * 32 + ni * 16 + fr;
                    float e = expf(acc[mi][ni][r]);
                    es += e; sa += ag2[ni] * e;
                    Cb[(size_t)row * N + col] = f2bf(e - 1.f);
                }
                #pragma unroll
                for (int m = 8; m; m >>= 1) { es += __shfl_xor(es, m); sa += __shfl_xor(sa, m); }
                if (fr == 0) {
                    atomicAdd(&ssum[row * 4 + bcol], es);
                    atomicAdd(&sagm[row * 4 + bcol], sa);
                }
            }
    } else {
        float* C2 = Cf + (size_t)bz * zC;
        #pragma unroll
        for (int ni = 0; ni < NR; ++ni) {
            int col = j0 + wc * 32 + ni * 16 + fr;
            #pragma unroll
            for (int mi = 0; mi < MR; ++mi)
                #pragma unroll
                for (int r = 0; r < 4; ++r) {
                    int row = i0 + wr * 32 + mi * 16 + fg * 4 + r;
                    C2[(size_t)row * N + col] = acc[mi][ni][r];
                }
        }
    }
}

// ---------------- K_mid: wcred (1024) | agT from 8 wgp partials (128) | zero ssum/sagm (1)
//                  (verbatim R14, passed) ----------------
__global__ __launch_bounds__(256) void k_mid(const float* __restrict__ wcp,
                                             u16* __restrict__ wcb,
                                             const u16* __restrict__ xtn,
                                             const float* __restrict__ wgp,
                                             const float* __restrict__ cg,
                                             float* __restrict__ agT,
                                             float* __restrict__ zz) {
    int bid = blockIdx.x, tid = threadIdx.x;
    if (bid < 1024) {
        int i = (bid * 256 + tid) * 4;
        float4 a = *(const float4*)(wcp + i);
        float4 b = *(const float4*)(wcp + 1048576 + i);
        float4 c = *(const float4*)(wcp + 2097152 + i);
        float4 d = *(const float4*)(wcp + 3145728 + i);
        ushort4 o;
        o.x = f2bf(a.x + b.x + c.x + d.x);
        o.y = f2bf(a.y + b.y + c.y + d.y);
        o.z = f2bf(a.z + b.z + c.z + d.z);
        o.w = f2bf(a.w + b.w + c.w + d.w);
        *(ushort4*)(wcb + i) = o;
    } else if (bid < 1152) {
        int t2 = bid - 1024;
        int b = t2 >> 5, ms = t2 & 31;
        int w = tid >> 6, lane = tid & 63;
        __shared__ float wgel[8192];
        __shared__ float cgl[8];
        #pragma unroll
        for (int i = 0; i < 8; ++i) {
            int idx = (tid + i * 256) * 4;
            float4 s = *(const float4*)&wgp[idx];
            #pragma unroll
            for (int eq = 1; eq < 8; ++eq) {
                float4 p = *(const float4*)&wgp[(size_t)eq * 8192 + idx];
                s.x += p.x; s.y += p.y; s.z += p.z; s.w += p.w;
            }
            *(float4*)&wgel[idx] = s;
        }
        if (tid < 8) cgl[tid] = cg[tid];
        __syncthreads();
        for (int r = 0; r < 8; ++r) {
            int m = ms * 32 + w * 8 + r;
            const u16* xr = xtn + ((size_t)b * 1024 + m) * 1024;
            float acc[8] = {};
            #pragma unroll
            for (int i = 0; i < 2; ++i) {
                int c0 = i * 512 + lane * 8;
                bf16x8 hv = *(const bf16x8*)(xr + c0);
                float xf[8];
                #pragma unroll
                for (int j = 0; j < 8; ++j) xf[j] = bf2f((u16)hv[j]);
                #pragma unroll
                for (int g = 0; g < 8; ++g) {
                    float4 wa = *(const float4*)&wgel[g * 1024 + c0];
                    float4 wb = *(const float4*)&wgel[g * 1024 + c0 + 4];
                    acc[g] += xf[0] * wa.x + xf[1] * wa.y + xf[2] * wa.z + xf[3] * wa.w
                            + xf[4] * wb.x + xf[5] * wb.y + xf[6] * wb.z + xf[7] * wb.w;
                }
            }
            #pragma unroll
            for (int g = 0; g < 8; ++g)
                #pragma unroll
                for (int off = 32; off; off >>= 1) acc[g] += __shfl_xor(acc[g], off);
            if (lane < 8)
                agT[((size_t)b * 8 + lane) * 1024 + m] =
                    1.f / (1.f + expf(-(acc[lane] + cgl[lane])));
        }
    } else {
        float4 z = make_float4(0.f, 0.f, 0.f, 0.f);
        #pragma unroll
        for (int i = 0; i < 8; ++i)
            *(float4*)&zz[(tid + i * 256) * 4] = z;
    }
}

// ---------------- K_wfx2: fused wf + wfx, ONE g PER BLOCK.  grid (32: ms*4+cs, b 4, g 8) = 1024 blocks
// wf[b,g,m] = ag[m]*(C0_g + sum_k c1[g,k]*em1[gk][m]), c1 = Wf/ssum (16K FMA, recomputed per cs).
// wfxp[ms][b][g][c] = sum_{m in seg} wf[g,m]*xtn[b,m,c].  u written by (ms==0,cs==0) block.
__global__ __launch_bounds__(256) void k_wfx2(const u16* __restrict__ em1,
                                              const float* __restrict__ ssum,
                                              const float* __restrict__ sagm,
                                              const float* __restrict__ Wf,
                                              const float* __restrict__ agT,
                                              const u16* __restrict__ xtn,
                                              float* __restrict__ wfxp,
                                              float* __restrict__ u) {
    int ms = blockIdx.x >> 2, cs = blockIdx.x & 3;
    int b = blockIdx.y, g = blockIdx.z;
    int tid = threadIdx.x;
    __shared__ float c1[128];
    __shared__ float wf_l[128];
    __shared__ float part[256];
    // phase A1: c1 = Wf/ssum, C0 = sum(c1), u (once)
    if (tid < 128) {
        int gk = g * 128 + tid;
        float cv = Wf[tid] / ssum[gk * 4 + b];
        c1[tid] = cv;
        part[tid] = cv;
        if (ms == 0 && cs == 0) u[(size_t)b * 1024 + gk] = cv * sagm[gk * 4 + b];
    } else part[tid] = 0.f;
    __syncthreads();
    for (int st = 128; st; st >>= 1) { if (tid < st) part[tid] += part[tid + st]; __syncthreads(); }
    float C0 = part[0];
    __syncthreads();
    // phase A2: wf for this (b,g,ms): 2 threads per m (k halves)
    {
        int ml = tid & 127, kh = tid >> 7;
        const u16* base = em1 + (size_t)(g * 128 + kh * 64) * 4096 + b * 1024 + ms * 128;
        float acc = 0.f;
        #pragma unroll 4
        for (int k = 0; k < 64; ++k)
            acc += c1[kh * 64 + k] * bf2f(base[(size_t)k * 4096 + ml]);
        part[tid] = acc;
    }
    __syncthreads();
    if (tid < 128) {
        float agv = agT[((size_t)b * 8 + g) * 1024 + ms * 128 + tid];
        wf_l[tid] = (C0 + part[tid] + part[tid + 128]) * agv;
    }
    __syncthreads();
    // phase B: wfx for this cs (256 c), 128 m
    int c = cs * 256 + tid;
    float acc = 0.f;
    const u16* xb = xtn + ((size_t)b * 1024 + ms * 128) * 1024 + c;
    #pragma unroll 4
    for (int m = 0; m < 128; ++m) acc += wf_l[m] * bf2f(xb[(size_t)m * 1024]);
    wfxp[(((size_t)ms * 4 + b) * 8 + g) * 1024 + c] = acc;
}

// ---------------- K_vfpart: ONE b PER BLOCK.  grid (8 g, 9 cs, 4 b) = 288 blocks
__global__ __launch_bounds__(256) void k_vfpart(const float* __restrict__ wfxp,
                                                const u16* __restrict__ winpT,
                                                const float* __restrict__ u,
                                                const float* __restrict__ cent,
                                                const float* __restrict__ binp,
                                                float* __restrict__ vfp) {
    int g = blockIdx.x, cs = blockIdx.y, bb = blockIdx.z;
    int tid = threadIdx.x;
    if (cs < 8) {
        __shared__ float wfx_l[128];
        if (tid < 128) {
            float s = 0.f;
            #pragma unroll
            for (int msq = 0; msq < 8; ++msq)
                s += wfxp[(((size_t)msq * 4 + bb) * 8 + g) * 1024 + cs * 128 + tid];
            wfx_l[tid] = s;
        }
        __syncthreads();
        int d = tid;
        float acc = 0.f;
        #pragma unroll 4
        for (int c2 = 0; c2 < 128; ++c2)
            acc += wfx_l[c2] * bf2f(winpT[(size_t)(cs * 128 + c2) * 2048 + g * 256 + d]);
        vfp[(((size_t)bb * 8 + g) * 9 + cs) * 256 + d] = acc;
    } else {
        __shared__ float ul[128];
        __shared__ float swl;
        if (tid < 128) ul[tid] = u[((size_t)bb * 8 + g) * 128 + tid];
        __syncthreads();
        if (tid < 64) {
            float s = ul[tid] + ul[tid + 64];
            #pragma unroll
            for (int m = 32; m; m >>= 1) s += __shfl_xor(s, m);
            if (tid == 0) swl = s;
        }
        __syncthreads();
        int d = tid;
        float acc = 0.f;
        #pragma unroll 4
        for (int k = 0; k < 128; ++k) acc -= ul[k] * cent[k * 256 + d];
        vfp[(((size_t)bb * 8 + g) * 9 + 8) * 256 + d] = acc + swl * binp[g * 256 + d];
    }
}

// ---------------- K_fin: finalize vf -> rank-8 NS -> coalesced triuvec (verbatim R14) ----------------
#define MM8(DST, P, Q) do { if (act) { float s_ = 0.f; \
    _Pragma("unroll") \
    for (int l_ = 0; l_ < 8; ++l_) s_ += P[ii][l_] * Q[l_][jj]; \
    DST[ii][jj] = s_; } __syncthreads(); } while (0)

__global__ __launch_bounds__(256) void k_fin(const float* __restrict__ vfp,
                                             const float* __restrict__ bf,
                                             float* __restrict__ out) {
    int slice = blockIdx.x, b = blockIdx.y;
    int tid = threadIdx.x, d = tid;
    __shared__ float Vl[256][9];
    __shared__ float4 Vl4a[256], Vl4b[256];
    __shared__ float Wr_l[256][8];
    __shared__ float red[256];
    __shared__ float Sp[4][64];
    __shared__ float Sm[8][8], W1[8][8], W2[8][8], YmL[8][8], ZmL[8][8], ZYL[8][8], FmL[8][8];
    float bfv = bf[0];
    float vfl[8];
    #pragma unroll
    for (int g = 0; g < 8; ++g) {
        float acc = 0.f;
        for (int mc = 0; mc < 9; ++mc)
            acc += vfp[(((size_t)b * 8 + g) * 9 + mc) * 256 + d];
        vfl[g] = acc + bfv;
    }
    float mean = 0.f;
    #pragma unroll
    for (int g = 0; g < 8; ++g) mean += vfl[g];
    mean *= 0.125f;
    float trp = 0.f;
    #pragma unroll
    for (int g = 0; g < 8; ++g) { float v = vfl[g] - mean; Vl[d][g] = v; vfl[g] = v; trp += v * v; }
    Vl4a[d] = make_float4(vfl[0], vfl[1], vfl[2], vfl[3]);
    Vl4b[d] = make_float4(vfl[4], vfl[5], vfl[6], vfl[7]);
    red[tid] = trp;
    __syncthreads();
    for (int s = 128; s > 0; s >>= 1) { if (tid < s) red[tid] += red[tid + s]; __syncthreads(); }
    float tr = red[0] * 0.125f;  // trace(cov)
    {
        int q = tid >> 6, l = tid & 63;
        int si = l >> 3, sj = l & 7;
        float sv = 0.f;
        for (int dd = q * 64; dd < q * 64 + 64; ++dd) sv += Vl[dd][si] * Vl[dd][sj];
        Sp[q][l] = sv;
    }
    __syncthreads();
    bool act = tid < 64;
    int ii = (tid >> 3) & 7, jj = tid & 7;
    if (act) Sm[ii][jj] = (Sp[0][tid] + Sp[1][tid] + Sp[2][tid] + Sp[3][tid]) / (8.f * tr);
    __syncthreads();
    if (act) {
        YmL[ii][jj] = (ii == jj ? 1.5f : 0.f) - 0.5f * Sm[ii][jj];
        ZmL[ii][jj] = (ii == jj ? -0.5f : 0.f);
    }
    __syncthreads();
    float ya = 0.f, za = 1.5f;
    MM8(W1, Sm, YmL);
    MM8(W2, ZmL, W1);
    float pa = za * ya;
    if (act) ZYL[ii][jj] = -0.5f * (za * YmL[ii][jj] + ya * ZmL[ii][jj] + W2[ii][jj]);
    __syncthreads();
    float zya = 1.5f - 0.5f * pa;
    MM8(W1, Sm, ZYL);
    MM8(W2, YmL, W1);
    if (act) YmL[ii][jj] = ya * ZYL[ii][jj] + zya * YmL[ii][jj] + W2[ii][jj];
    __syncthreads();
    ya = ya * zya;
    MM8(W1, Sm, ZmL);
    MM8(W2, ZYL, W1);
    if (act) ZmL[ii][jj] = zya * ZmL[ii][jj] + za * ZYL[ii][jj] + W2[ii][jj];
    __syncthreads();
    za = zya * za;
    MM8(W1, Sm, YmL);
    MM8(W2, ZmL, W1);
    float p2a = za * ya;
    if (act) ZYL[ii][jj] = za * YmL[ii][jj] + ya * ZmL[ii][jj] + W2[ii][jj];
    __syncthreads();
    MM8(W1, Sm, ZYL);
    MM8(W2, YmL, W1);
    if (act) FmL[ii][jj] = 0.5f * ((3.f - p2a) * YmL[ii][jj] - ya * ZYL[ii][jj] - W2[ii][jj]);
    __syncthreads();
    float fa = 0.5f * ya * (3.f - p2a);
    float sqtr = sqrtf(tr);
    float scaleF = 1.f / (8.f * sqtr);
    #pragma unroll
    for (int jo = 0; jo < 8; ++jo) {
        float sv = 0.f;
        #pragma unroll
        for (int i = 0; i < 8; ++i) sv += vfl[i] * FmL[i][jo];
        Wr_l[d][jo] = sv * scaleF;
    }
    float s0v = fa * sqtr;
    __syncthreads();
    int dd0 = slice * 32;
    for (int dd = dd0; dd < dd0 + 32; ++dd) {
        int e = tid;
        if (e >= dd) {
            float w0 = Wr_l[dd][0], w1 = Wr_l[dd][1], w2 = Wr_l[dd][2], w3 = Wr_l[dd][3];
            float w4 = Wr_l[dd][4], w5 = Wr_l[dd][5], w6 = Wr_l[dd][6], w7 = Wr_l[dd][7];
            float4 va = Vl4a[e], vb = Vl4b[e];
            float v = w0 * va.x + w1 * va.y + w2 * va.z + w3 * va.w
                    + w4 * vb.x + w5 * vb.y + w6 * vb.z + w7 * vb.w;
            if (e == dd) v += s0v;
            size_t base = (size_t)b * 32896 + (size_t)dd * 256 - ((size_t)dd * (dd - 1)) / 2;
            out[base + (e - dd)] = v;
        }
    }
}

extern "C" void kernel_launch(void* const* d_in, const int* in_sizes, int n_in,
                              void* d_out, int out_size, void* d_ws, size_t ws_size,
                              hipStream_t stream) {
    const float* x    = (const float*)d_in[0];
    const float* cent = (const float*)d_in[1];
    const float* Winp = (const float*)d_in[2];
    const float* binp = (const float*)d_in[3];
    const float* Wg   = (const float*)d_in[4];
    const float* bg   = (const float*)d_in[5];
    const float* Wgk  = (const float*)d_in[6];
    const float* Wf   = (const float*)d_in[8];
    const float* bf   = (const float*)d_in[9];
    float* out = (float*)d_out;
    char* wsb = (char*)d_ws;

    // byte-offset workspace layout
    u16*   xtnb  = (u16*)(wsb);                          // [4096][1024] bf16, 8 MB
    u16*   ltb   = (u16*)(wsb + (8ull << 20));           // em1 [1024][4096] bf16, 8 MB
    u16*   wgkb  = (u16*)(wsb + (16ull << 20));          // [1024][2048] bf16, 4 MB
    u16*   winpT = (u16*)(wsb + (20ull << 20));          // [1024][2048] bf16, 4 MB
    float* wcp   = (float*)(wsb + (24ull << 20));        // [4][1024][1024] f32, 16 MB
    u16*   wcb   = (u16*)(wsb + (40ull << 20));          // [1024][1024] bf16, 2 MB
    float* misc  = (float*)(wsb + (42ull << 20));
    float* wgp   = misc;                 // [8][8][1024] partials
    float* cg    = wgp + 65536;          // [8]
    float* ssum  = cg + 8;               // [1024][4]  (zeroed by k_mid)
    float* sagm  = ssum + 4096;          // [1024][4]
    float* agT   = sagm + 4096;          // [4][8][1024]
    float* u     = agT + 32768;          // [4][1024]
    float* wfxp  = u + 4096;             // [8][4][8][1024]
    float* vfp   = wfxp + 262144;        // [4][8][9][256]
    float* normp = vfp + 73728;          // [16][4096] norm partials

    k_pre<<<3105, 256, 0, stream>>>(x, Wgk, Winp, Wg, binp, bg, wgkb, winpT, wgp, cg, normp);
    // Wc GEMM (z 0..3) + transpose phase-2 (z 4..5): 1536 blocks
    k_mfma_gemm<0><<<dim3(16, 16, 6), 256, 0, stream>>>(
        wgkb, winpT, wcp, nullptr, nullptr, nullptr, nullptr,
        x, normp, xtnb,
        2048, 512, 1024, 512LL, 512LL, 1048576LL);
    k_mid<<<1153, 256, 0, stream>>>(wcp, wcb, xtnb, wgp, cg, agT, ssum);
    // logits: em1[gk][b*1024+m] = exp(Wc @ xtn^T) - 1 (bf16) + atomic ssum/sagm
    k_mfma_gemm<3><<<dim3(64, 16, 1), 256, 0, stream>>>(
        wcb, xtnb, nullptr, ltb, agT, ssum, sagm,
        nullptr, nullptr, nullptr,
        1024, 1024, 4096, 0, 0, 0);
    k_wfx2<<<dim3(32, 4, 8), 256, 0, stream>>>(ltb, ssum, sagm, Wf, agT, xtnb, wfxp, u);
    k_vfpart<<<dim3(8, 9, 4), 256, 0, stream>>>(wfxp, winpT, u, cent, binp, vfp);
    k_fin<<<dim3(8, 4), 256, 0, stream>>>(vfp, bf, out);
}